// Round 9
// baseline (549.792 us; speedup 1.0000x reference)
//
#include <hip/hip_runtime.h>
#include <hip/hip_bf16.h>

typedef __attribute__((ext_vector_type(8))) short short8;
typedef __attribute__((ext_vector_type(16))) float f32x16;
typedef __attribute__((ext_vector_type(4))) float f32x4;
typedef __attribute__((ext_vector_type(4))) unsigned int uint4v;
typedef __attribute__((ext_vector_type(4))) unsigned short ushort4v;

__device__ __forceinline__ float silu_f(float v) {
    return v * __builtin_amdgcn_rcpf(1.0f + __expf(-v));
}
__device__ __forceinline__ unsigned short bfhi(float v) {
    __hip_bfloat16 h = __float2bfloat16(v);
    return *reinterpret_cast<unsigned short*>(&h);
}
__device__ __forceinline__ float bf2f(unsigned short u) {
    __hip_bfloat16 h;
    *reinterpret_cast<unsigned short*>(&h) = u;
    return __bfloat162float(h);
}

// ======= weight prep: f32 -> bf16 hi/lo fragments (pf*1024 + lane*8, lo +512)
// arena (in d_out): conv1 @0 (36pf), wc0 @36 (8pf), wb1 @44 (18pf),
//   wb2 @62 (18pf), wc1 @80 (12pf), w0 @92 (2pf; K=32 padded from 27). 94 pf.
__global__ __launch_bounds__(256) void prep_small(
    const float* __restrict__ w1, const float* __restrict__ wc0,
    const float* __restrict__ wb1, const float* __restrict__ wb2,
    const float* __restrict__ wc1, const float* __restrict__ w0,
    unsigned short* __restrict__ arena)
{
    const int u = blockIdx.x * 256 + threadIdx.x;   // 0..6015
    if (u >= 6016) return;
    const int lane = u & 63, pf = u >> 6;
    float wv[8];
    if (pf < 36) {
        const int q = pf, cc = q & 1, rnd = (q >> 1) & 1, tap = q >> 2;
        const int co = cc * 32 + (lane & 31), ci0 = rnd * 16 + (lane >> 5) * 8;
        #pragma unroll
        for (int j = 0; j < 8; ++j) wv[j] = w1[(co * 32 + ci0 + j) * 9 + tap];
    } else if (pf < 44) {
        const int q = pf - 36, cc = q & 1, rnd = q >> 1;
        const int co = cc * 32 + (lane & 31), ci0 = rnd * 16 + (lane >> 5) * 8;
        #pragma unroll
        for (int j = 0; j < 8; ++j) wv[j] = wc0[co * 64 + ci0 + j];
    } else if (pf < 62) {
        const int q = pf - 44, rnd = q & 1, tap = q >> 1;
        const int co = lane & 31, ci0 = rnd * 16 + (lane >> 5) * 8;
        #pragma unroll
        for (int j = 0; j < 8; ++j) wv[j] = wb1[(co * 32 + ci0 + j) * 9 + tap];
    } else if (pf < 80) {
        const int q = pf - 62, rnd = q & 1, tap = q >> 1;
        const int co = lane & 31, ci0 = rnd * 16 + (lane >> 5) * 8;
        #pragma unroll
        for (int j = 0; j < 8; ++j) wv[j] = wb2[(co * 32 + ci0 + j) * 9 + tap];
    } else if (pf < 92) {
        const int q = pf - 80, cc = q & 1, rnd = q >> 1;
        const int co = cc * 32 + (lane & 31), ci0 = rnd * 16 + (lane >> 5) * 8;
        #pragma unroll
        for (int j = 0; j < 8; ++j) wv[j] = wc1[co * 96 + ci0 + j];
    } else {
        const int co = lane & 31;
        const int k0 = (pf - 92) * 16 + (lane >> 5) * 8;
        #pragma unroll
        for (int j = 0; j < 8; ++j) {
            const int k = k0 + j;
            wv[j] = (k < 27) ? w0[(co * 3 + k / 9) * 9 + (k % 9)] : 0.0f;
        }
    }
    unsigned short hs[8], ls[8];
    #pragma unroll
    for (int j = 0; j < 8; ++j) {
        unsigned short hh = bfhi(wv[j]);
        hs[j] = hh; ls[j] = bfhi(wv[j] - bf2f(hh));
    }
    *reinterpret_cast<short8*>(&arena[pf * 1024 + lane * 8])       = *(short8*)hs;
    *reinterpret_cast<short8*>(&arena[pf * 1024 + 512 + lane * 8]) = *(short8*)ls;
}

// arena2 (in ws): w3, pf = ((cg*9+tap)*4 + kc)*2+cc, kc = ci/16. 144 pf
__global__ __launch_bounds__(256) void prep_w3(
    const float* __restrict__ w3, unsigned short* __restrict__ arena)
{
    const int u = blockIdx.x * 256 + threadIdx.x;   // 0..9215
    const int lane = u & 63, pf = u >> 6;
    const int cc = pf & 1, kc = (pf >> 1) & 3, t9 = pf >> 3;
    const int tap = t9 % 9, cg = t9 / 9;
    const int co = cg * 64 + cc * 32 + (lane & 31);
    const int ci0 = kc * 16 + (lane >> 5) * 8;
    unsigned short hs[8], ls[8];
    #pragma unroll
    for (int j = 0; j < 8; ++j) {
        float wv = w3[(co * 64 + ci0 + j) * 9 + tap];
        unsigned short hh = bfhi(wv);
        hs[j] = hh; ls[j] = bfhi(wv - bf2f(hh));
    }
    *reinterpret_cast<short8*>(&arena[pf * 1024 + lane * 8])       = *(short8*)hs;
    *reinterpret_cast<short8*>(&arena[pf * 1024 + 512 + lane * 8]) = *(short8*)ls;
}

// ============ conv0: 3->32 s2 as K=32 gather-GEMM (MFMA), parity out ========
__global__ __launch_bounds__(512, 4) void conv0_mfma(
    const float* __restrict__ x, const unsigned short* __restrict__ wfr,
    const float* __restrict__ bias, unsigned short* __restrict__ out)
{
    const int tid = threadIdx.x;
    const int wv = tid >> 6, lane = tid & 63;
    const int p = lane & 31, h = lane >> 5;
    const int plane = blockIdx.y;
    const int pyp = plane >> 1, pxp = plane & 1;
    const int pp = blockIdx.x * 256 + wv * 32 + p;
    const int n = blockIdx.z;
    const int Y = 2 * (pp / 160) + pyp, X = 2 * (pp % 160) + pxp;

    int off[16]; float msk[16];
    #pragma unroll
    for (int rnd = 0; rnd < 2; ++rnd)
        #pragma unroll
        for (int j = 0; j < 8; ++j) {
            const int kidx = rnd * 16 + h * 8 + j;
            const int idx = rnd * 8 + j;
            if (kidx < 27) {
                const int ci = kidx / 9, tap = kidx - ci * 9;
                const int iy = 2 * Y + (tap / 3) - 1;
                const int ix = 2 * X + (tap % 3) - 1;
                const bool ok = (iy >= 0) && (iy < 640) && (ix >= 0) && (ix < 640);
                const int cy = min(max(iy, 0), 639), cx = min(max(ix, 0), 639);
                off[idx] = ci * 409600 + cy * 640 + cx;
                msk[idx] = ok ? 1.0f : 0.0f;
            } else {
                off[idx] = 0; msk[idx] = 0.0f;
            }
        }

    f32x16 acc;
    #pragma unroll
    for (int q = 0; q < 4; ++q) {
        f32x4 b4 = *reinterpret_cast<const f32x4*>(&bias[q * 8 + 4 * h]);
        #pragma unroll
        for (int r = 0; r < 4; ++r) acc[q * 4 + r] = b4[r];
    }

    const float* xb = x + (long)n * 1228800;
    #pragma unroll
    for (int rnd = 0; rnd < 2; ++rnd) {
        unsigned short hs[8], ls[8];
        #pragma unroll
        for (int j = 0; j < 8; ++j) {
            float v = xb[off[rnd * 8 + j]] * msk[rnd * 8 + j];
            unsigned short hh = bfhi(v);
            hs[j] = hh; ls[j] = bfhi(v - bf2f(hh));
        }
        short8 Bh = *(short8*)hs, Bl = *(short8*)ls;
        const unsigned short* fb = wfr + (92 + rnd) * 1024 + lane * 8;
        short8 Awh = *reinterpret_cast<const short8*>(fb);
        short8 Awl = *reinterpret_cast<const short8*>(fb + 512);
        acc = __builtin_amdgcn_mfma_f32_32x32x16_bf16(Awh, Bh, acc, 0, 0, 0);
        acc = __builtin_amdgcn_mfma_f32_32x32x16_bf16(Awh, Bl, acc, 0, 0, 0);
        acc = __builtin_amdgcn_mfma_f32_32x32x16_bf16(Awl, Bh, acc, 0, 0, 0);
    }

    unsigned short* op = out + (((long)n * 4 + plane) * 25600 + pp) * 64;
    #pragma unroll
    for (int q = 0; q < 4; ++q) {
        ushort4v hv, lv;
        #pragma unroll
        for (int r = 0; r < 4; ++r) {
            float v = silu_f(acc[q * 4 + r]);
            unsigned short hh = bfhi(v);
            hv[r] = hh; lv[r] = bfhi(v - bf2f(hh));
        }
        *reinterpret_cast<ushort4v*>(op + q * 16 + 4 * h)     = hv;
        *reinterpret_cast<ushort4v*>(op + q * 16 + 8 + 4 * h) = lv;
    }
}

// ============ conv1: 32->64 s2 3x3 + FUSED wc0, kind-split rounds ===========
// input tile staged per (ci-half, kind): 16 ush/rec -> LDS 35.4 KB
__global__ __launch_bounds__(512, 6) void conv1_fused(
    const unsigned short* __restrict__ h0, const unsigned short* __restrict__ wfr,
    const unsigned short* __restrict__ wc0fr, const float* __restrict__ bias,
    const float* __restrict__ bc0, unsigned short* __restrict__ ycl)
{
    __shared__ unsigned short lds[17680];        // 1105 recs x 16 ush (35.4 KB)
    const int tid = threadIdx.x;
    const int wv = tid >> 6, lane = tid & 63;
    const int p = lane & 31, h = lane >> 5;
    const int bx = blockIdx.x % 5, by = blockIdx.x / 5;
    const int ox0 = bx * 32, oy0 = by * 8;
    const int n = blockIdx.z;

    f32x16 acc[2];
    #pragma unroll
    for (int cc = 0; cc < 2; ++cc)
        #pragma unroll
        for (int q = 0; q < 4; ++q) {
            f32x4 b4 = *reinterpret_cast<const f32x4*>(&bias[cc * 32 + q * 8 + 4 * h]);
            #pragma unroll
            for (int r = 0; r < 4; ++r) acc[cc][q * 4 + r] = b4[r];
        }

    for (int rr = 0; rr < 4; ++rr) {
        const int c = rr >> 1, k = rr & 1;
        __syncthreads();
        // parity tiles: ee[0,256)W32, eo[256,520)W33, oe[520,808)W32, oo[808,1105)W33
        for (int u = tid; u < 2210; u += 512) {
            const int rec = u >> 1, s = u & 1;
            int gp, row, col;
            if (rec < 256)      { gp = 0; row = rec >> 5;  col = rec & 31; }
            else if (rec < 520) { gp = 1; int r2 = rec - 256; row = r2 / 33; col = r2 - row * 33; }
            else if (rec < 808) { gp = 2; int r2 = rec - 520; row = r2 >> 5; col = r2 & 31; }
            else                { gp = 3; int r2 = rec - 808; row = r2 / 33; col = r2 - row * 33; }
            const int gr = (gp >= 2) ? oy0 - 1 + row : oy0 + row;
            const int gc = (gp & 1)  ? ox0 - 1 + col : ox0 + col;
            uint4v val = {0, 0, 0, 0};
            if (gr >= 0 && gr < 160 && gc >= 0 && gc < 160)
                val = *reinterpret_cast<const uint4v*>(
                    h0 + (((long)n * 4 + gp) * 25600 + gr * 160 + gc) * 64 + (4 * c + 2 * s + k) * 8);
            *reinterpret_cast<uint4v*>(&lds[rec * 16 + ((s ^ (rec & 1)) * 8)]) = val;
        }
        __syncthreads();

        #pragma unroll
        for (int tap = 0; tap < 9; ++tap) {
            const int dy = tap / 3 - 1, dx = tap % 3 - 1;
            const int ppy = dy & 1, ppx = dx & 1;
            const int toy = ppy ? ((dy == -1) ? 0 : 1) : 0;
            const int tox = ppx ? ((dx == -1) ? 0 : 1) : 0;
            const int gp = ppy * 2 + ppx;
            const int base = (gp == 0) ? 0 : (gp == 1) ? 256 : (gp == 2) ? 520 : 808;
            const int W = ppx ? 33 : 32;
            const int rec = base + (ppy ? (wv + toy) : wv) * W + (p + tox);
            short8 Bq = *reinterpret_cast<const short8*>(&lds[rec * 16 + ((h ^ (rec & 1)) * 8)]);
            #pragma unroll
            for (int cc = 0; cc < 2; ++cc) {
                const unsigned short* fb = wfr + ((tap * 2 + c) * 2 + cc) * 1024 + lane * 8;
                short8 Awh = *reinterpret_cast<const short8*>(fb);
                if (k == 0) {
                    short8 Awl = *reinterpret_cast<const short8*>(fb + 512);
                    acc[cc] = __builtin_amdgcn_mfma_f32_32x32x16_bf16(Awh, Bq, acc[cc], 0, 0, 0);
                    acc[cc] = __builtin_amdgcn_mfma_f32_32x32x16_bf16(Awl, Bq, acc[cc], 0, 0, 0);
                } else {
                    acc[cc] = __builtin_amdgcn_mfma_f32_32x32x16_bf16(Awh, Bq, acc[cc], 0, 0, 0);
                }
            }
        }
    }

    // ---- wc0 fused: 4 (ch,kind) rounds; stage y-slice to LDS, MFMA from it
    f32x16 a2[2];
    #pragma unroll
    for (int cc = 0; cc < 2; ++cc)
        #pragma unroll
        for (int q = 0; q < 4; ++q) {
            f32x4 b4 = *reinterpret_cast<const f32x4*>(&bc0[cc * 32 + q * 8 + 4 * h]);
            #pragma unroll
            for (int r = 0; r < 4; ++r) a2[cc][q * 4 + r] = b4[r];
        }
    const int rec = wv * 32 + p;
    for (int rr = 0; rr < 4; ++rr) {
        const int ch = rr >> 1, k = rr & 1;
        __syncthreads();
        #pragma unroll
        for (int q = 0; q < 4; ++q) {
            ushort4v w4;
            #pragma unroll
            for (int r = 0; r < 4; ++r) {
                float v = silu_f(acc[ch][q * 4 + r]);
                unsigned short hh = bfhi(v);
                w4[r] = (k == 0) ? hh : bfhi(v - bf2f(hh));
            }
            *reinterpret_cast<ushort4v*>(&lds[rec * 32 + ((q ^ (rec & 3)) * 8) + 4 * h]) = w4;
        }
        __syncthreads();
        #pragma unroll
        for (int rnd2 = 0; rnd2 < 2; ++rnd2) {
            short8 Bq = *reinterpret_cast<const short8*>(
                &lds[rec * 32 + (((rnd2 * 2 + h) ^ (rec & 3)) * 8)]);
            #pragma unroll
            for (int cc = 0; cc < 2; ++cc) {
                const unsigned short* fb = wc0fr + ((ch * 2 + rnd2) * 2 + cc) * 1024 + lane * 8;
                short8 Awh = *reinterpret_cast<const short8*>(fb);
                if (k == 0) {
                    short8 Awl = *reinterpret_cast<const short8*>(fb + 512);
                    a2[cc] = __builtin_amdgcn_mfma_f32_32x32x16_bf16(Awh, Bq, a2[cc], 0, 0, 0);
                    a2[cc] = __builtin_amdgcn_mfma_f32_32x32x16_bf16(Awl, Bq, a2[cc], 0, 0, 0);
                } else {
                    a2[cc] = __builtin_amdgcn_mfma_f32_32x32x16_bf16(Awh, Bq, a2[cc], 0, 0, 0);
                }
            }
        }
    }

    const int oy = oy0 + wv;
    unsigned short* op = ycl + ((long)n * 25600 + (long)oy * 160 + ox0 + p) * 128;
    #pragma unroll
    for (int cc = 0; cc < 2; ++cc)
        #pragma unroll
        for (int q = 0; q < 4; ++q) {
            ushort4v hv, lv;
            #pragma unroll
            for (int r = 0; r < 4; ++r) {
                float v = silu_f(a2[cc][q * 4 + r]);
                unsigned short hh = bfhi(v);
                hv[r] = hh; lv[r] = bfhi(v - bf2f(hh));
            }
            const int gq = cc * 4 + q;
            *reinterpret_cast<ushort4v*>(op + gq * 16 + 4 * h)     = hv;
            *reinterpret_cast<ushort4v*>(op + gq * 16 + 8 + 4 * h) = lv;
        }
}

// ============ wb: 32->32 s1 3x3, 2 ci-half rounds -> LDS 21.8 KB ============
template <bool RESID>
__global__ __launch_bounds__(512, 8) void wb3x3(
    const unsigned short* __restrict__ in, int inRec, int inSlot0,
    const unsigned short* __restrict__ wfr, const float* __restrict__ bias,
    unsigned short* __restrict__ outb, const unsigned short* __restrict__ resid)
{
    __shared__ unsigned short lds[10880];        // 340 recs x 32 ush (21.8 KB)
    const int tid = threadIdx.x;
    const int wv = tid >> 6, lane = tid & 63;
    const int p = lane & 31, h = lane >> 5;
    const int bx = blockIdx.x % 5, by = blockIdx.x / 5;
    const int ox0 = bx * 32, oy0 = by * 8;
    const int n = blockIdx.z;

    f32x16 acc;
    #pragma unroll
    for (int q = 0; q < 4; ++q) {
        f32x4 b4 = *reinterpret_cast<const f32x4*>(&bias[q * 8 + 4 * h]);
        #pragma unroll
        for (int r = 0; r < 4; ++r) acc[q * 4 + r] = b4[r];
    }

    for (int c = 0; c < 2; ++c) {
        __syncthreads();
        for (int u = tid; u < 1360; u += 512) {  // tile 34x10, 4 slots/rec
            const int rec = u >> 2, s = u & 3;
            const int row = rec / 34, col = rec - row * 34;
            const int gr = oy0 - 1 + row, gc = ox0 - 1 + col;
            uint4v val = {0, 0, 0, 0};
            if (gr >= 0 && gr < 160 && gc >= 0 && gc < 160)
                val = *reinterpret_cast<const uint4v*>(
                    in + ((long)n * 25600 + gr * 160 + gc) * inRec + (inSlot0 + 4 * c + s) * 8);
            *reinterpret_cast<uint4v*>(&lds[rec * 32 + ((s ^ (rec & 3)) * 8)]) = val;
        }
        __syncthreads();

        #pragma unroll
        for (int tap = 0; tap < 9; ++tap) {
            const int dy = tap / 3 - 1, dx = tap % 3 - 1;
            const int rec = (wv + dy + 1) * 34 + (p + dx + 1);
            const unsigned short* t = &lds[rec * 32];
            short8 Bh = *reinterpret_cast<const short8*>(t + (((2 * h)     ^ (rec & 3)) * 8));
            short8 Bl = *reinterpret_cast<const short8*>(t + (((2 * h + 1) ^ (rec & 3)) * 8));
            const unsigned short* fb = wfr + (tap * 2 + c) * 1024 + lane * 8;
            short8 Awh = *reinterpret_cast<const short8*>(fb);
            short8 Awl = *reinterpret_cast<const short8*>(fb + 512);
            acc = __builtin_amdgcn_mfma_f32_32x32x16_bf16(Awh, Bh, acc, 0, 0, 0);
            acc = __builtin_amdgcn_mfma_f32_32x32x16_bf16(Awh, Bl, acc, 0, 0, 0);
            acc = __builtin_amdgcn_mfma_f32_32x32x16_bf16(Awl, Bh, acc, 0, 0, 0);
        }
    }

    const int oy = oy0 + wv;
    const long prow = (long)n * 25600 + (long)oy * 160 + ox0 + p;
    unsigned short* op = outb + prow * 64;
    const unsigned short* rp = RESID ? resid + prow * 128 : nullptr;
    #pragma unroll
    for (int q = 0; q < 4; ++q) {
        ushort4v hv, lv;
        float vs[4];
        #pragma unroll
        for (int r = 0; r < 4; ++r) vs[r] = silu_f(acc[q * 4 + r]);
        if (RESID) {
            ushort4v rh = *reinterpret_cast<const ushort4v*>(rp + (q + 4) * 16 + 4 * h);
            ushort4v rl = *reinterpret_cast<const ushort4v*>(rp + (q + 4) * 16 + 8 + 4 * h);
            #pragma unroll
            for (int r = 0; r < 4; ++r) vs[r] += bf2f(rh[r]) + bf2f(rl[r]);
        }
        #pragma unroll
        for (int r = 0; r < 4; ++r) {
            unsigned short hh = bfhi(vs[r]);
            hv[r] = hh; lv[r] = bfhi(vs[r] - bf2f(hh));
        }
        *reinterpret_cast<ushort4v*>(op + q * 16 + 4 * h)     = hv;
        *reinterpret_cast<ushort4v*>(op + q * 16 + 8 + 4 * h) = lv;
    }
}

// ============ wc1: 1x1 concat(96->64), zero LDS, frags from global ==========
template <int R1, int R2, bool POUT>
__global__ __launch_bounds__(512, 4) void wc1x1(
    const unsigned short* __restrict__ in1, int rec1,
    const unsigned short* __restrict__ in2, int rec2,
    const unsigned short* __restrict__ wfr, const float* __restrict__ bias,
    unsigned short* __restrict__ outb)
{
    constexpr int RT = R1 + R2;
    const int tid = threadIdx.x;
    const int wv = tid >> 6, lane = tid & 63;
    const int p = lane & 31, h = lane >> 5;
    const int n = blockIdx.z;
    const int px0 = blockIdx.x * 512;

    f32x16 acc[2][2];
    #pragma unroll
    for (int cc = 0; cc < 2; ++cc)
        #pragma unroll
        for (int q = 0; q < 4; ++q) {
            f32x4 b4 = *reinterpret_cast<const f32x4*>(&bias[cc * 32 + q * 8 + 4 * h]);
            #pragma unroll
            for (int r = 0; r < 4; ++r) { acc[cc][0][q*4+r] = b4[r]; acc[cc][1][q*4+r] = b4[r]; }
        }

    #pragma unroll
    for (int rnd = 0; rnd < RT; ++rnd) {
        const unsigned short* bp = (rnd < R1) ? in1 : in2;
        const int recN = (rnd < R1) ? rec1 : rec2;
        const int s0 = 4 * ((rnd < R1) ? rnd : rnd - R1);
        #pragma unroll
        for (int k = 0; k < 2; ++k) {
            const int px = px0 + (wv * 2 + k) * 32 + p;
            const unsigned short* sp = bp + ((long)n * 25600 + px) * recN + (s0 + 2 * h) * 8;
            short8 Bh = *reinterpret_cast<const short8*>(sp);
            short8 Bl = *reinterpret_cast<const short8*>(sp + 8);
            #pragma unroll
            for (int cc = 0; cc < 2; ++cc) {
                const unsigned short* fb = wfr + (rnd * 2 + cc) * 1024 + lane * 8;
                short8 Awh = *reinterpret_cast<const short8*>(fb);
                short8 Awl = *reinterpret_cast<const short8*>(fb + 512);
                acc[cc][k] = __builtin_amdgcn_mfma_f32_32x32x16_bf16(Awh, Bh, acc[cc][k], 0, 0, 0);
                acc[cc][k] = __builtin_amdgcn_mfma_f32_32x32x16_bf16(Awh, Bl, acc[cc][k], 0, 0, 0);
                acc[cc][k] = __builtin_amdgcn_mfma_f32_32x32x16_bf16(Awl, Bh, acc[cc][k], 0, 0, 0);
            }
        }
    }

    #pragma unroll
    for (int k = 0; k < 2; ++k) {
        const int px = px0 + (wv * 2 + k) * 32 + p;
        unsigned short* op;
        if (POUT) {
            const int y = px / 160, xx = px % 160;
            const int pl = (y & 1) * 2 + (xx & 1);
            op = outb + (((long)n * 4 + pl) * 6400 + (y >> 1) * 80 + (xx >> 1)) * 128;
        } else {
            op = outb + ((long)n * 25600 + px) * 128;
        }
        #pragma unroll
        for (int cc = 0; cc < 2; ++cc)
            #pragma unroll
            for (int q = 0; q < 4; ++q) {
                ushort4v hv, lv;
                #pragma unroll
                for (int r = 0; r < 4; ++r) {
                    float v = silu_f(acc[cc][k][q * 4 + r]);
                    unsigned short hh = bfhi(v);
                    hv[r] = hh; lv[r] = bfhi(v - bf2f(hh));
                }
                const int gq = cc * 4 + q;
                *reinterpret_cast<ushort4v*>(op + gq * 16 + 4 * h)     = hv;
                *reinterpret_cast<ushort4v*>(op + gq * 16 + 8 + 4 * h) = lv;
            }
    }
}

// ============ conv3: 64->128 s2 3x3, single kernel, 8 kind-split rounds =====
// 16x8 out tile, wave = (pxgroup, cc); LDS 561 recs x 16 ush = 18 KB
__global__ __launch_bounds__(512, 8) void conv3_one(
    const unsigned short* __restrict__ h2p, const unsigned short* __restrict__ wfr,
    const float* __restrict__ bias, float* __restrict__ outf)
{
    __shared__ unsigned short lds[8976];         // 561 x 16 ush
    const int tid = threadIdx.x;
    const int wv = tid >> 6, lane = tid & 63;
    const int p = lane & 31, h = lane >> 5;
    const int wvp = wv & 3, wcc = wv >> 2;
    const int bx = blockIdx.x % 5, by = blockIdx.x / 5;
    const int ox0 = bx * 16, oy0 = by * 8;
    const int cg = blockIdx.y;
    const int co0 = cg * 64;
    const int n = blockIdx.z;

    f32x16 acc;
    #pragma unroll
    for (int q = 0; q < 4; ++q) {
        f32x4 b4 = *reinterpret_cast<const f32x4*>(&bias[co0 + wcc * 32 + q * 8 + 4 * h]);
        #pragma unroll
        for (int r = 0; r < 4; ++r) acc[q * 4 + r] = b4[r];
    }

    for (int rr = 0; rr < 8; ++rr) {
        const int kc = rr >> 1, k = rr & 1;
        __syncthreads();
        // parity tiles: ee[0,128)W16, eo[128,264)W17, oe[264,408)W16, oo[408,561)W17
        for (int u = tid; u < 1122; u += 512) {
            const int rec = u >> 1, s = u & 1;
            int gp, row, col;
            if (rec < 128)      { gp = 0; row = rec >> 4; col = rec & 15; }
            else if (rec < 264) { gp = 1; int r2 = rec - 128; row = r2 / 17; col = r2 - row * 17; }
            else if (rec < 408) { gp = 2; int r2 = rec - 264; row = r2 >> 4; col = r2 & 15; }
            else                { gp = 3; int r2 = rec - 408; row = r2 / 17; col = r2 - row * 17; }
            const int gr = (gp >= 2) ? oy0 - 1 + row : oy0 + row;
            const int gc = (gp & 1)  ? ox0 - 1 + col : ox0 + col;
            uint4v val = {0, 0, 0, 0};
            if (gr >= 0 && gr < 80 && gc >= 0 && gc < 80)
                val = *reinterpret_cast<const uint4v*>(
                    h2p + (((long)n * 4 + gp) * 6400 + gr * 80 + gc) * 128 + (4 * kc + 2 * s + k) * 8);
            *reinterpret_cast<uint4v*>(&lds[rec * 16 + ((s ^ (rec & 1)) * 8)]) = val;
        }
        __syncthreads();

        #pragma unroll
        for (int tap = 0; tap < 9; ++tap) {
            const int dy = tap / 3 - 1, dx = tap % 3 - 1;
            const int ppy = dy & 1, ppx = dx & 1;
            const int toy = ppy ? ((dy == -1) ? 0 : 1) : 0;
            const int tox = ppx ? ((dx == -1) ? 0 : 1) : 0;
            const int gp = ppy * 2 + ppx;
            const int base = (gp == 0) ? 0 : (gp == 1) ? 128 : (gp == 2) ? 264 : 408;
            const int W = ppx ? 17 : 16;
            const int rl = wvp * 2 + (p >> 4), cl = p & 15;
            const int rec = base + (ppy ? (rl + toy) : rl) * W + (cl + tox);
            short8 Bq = *reinterpret_cast<const short8*>(&lds[rec * 16 + ((h ^ (rec & 1)) * 8)]);
            const unsigned short* fb =
                wfr + (((cg * 9 + tap) * 4 + kc) * 2 + wcc) * 1024 + lane * 8;
            short8 Awh = *reinterpret_cast<const short8*>(fb);
            if (k == 0) {
                short8 Awl = *reinterpret_cast<const short8*>(fb + 512);
                acc = __builtin_amdgcn_mfma_f32_32x32x16_bf16(Awh, Bq, acc, 0, 0, 0);
                acc = __builtin_amdgcn_mfma_f32_32x32x16_bf16(Awl, Bq, acc, 0, 0, 0);
            } else {
                acc = __builtin_amdgcn_mfma_f32_32x32x16_bf16(Awh, Bq, acc, 0, 0, 0);
            }
        }
    }

    const int rl = wvp * 2 + (p >> 4);
    const int oy = oy0 + rl;
    const int pxg = oy * 80 + ox0 + (p & 15);
    #pragma unroll
    for (int q = 0; q < 4; ++q)
        #pragma unroll
        for (int r = 0; r < 4; ++r) {
            const int co = co0 + wcc * 32 + q * 8 + 4 * h + r;
            outf[((long)n * 128 + co) * 6400 + pxg] = silu_f(acc[q * 4 + r]);
        }
}

extern "C" void kernel_launch(void* const* d_in, const int* in_sizes, int n_in,
                              void* d_out, int out_size, void* d_ws, size_t ws_size,
                              hipStream_t stream) {
    const float* x   = (const float*)d_in[0];
    const float* w0  = (const float*)d_in[1];
    const float* b0  = (const float*)d_in[2];
    const float* w1  = (const float*)d_in[3];
    const float* b1  = (const float*)d_in[4];
    const float* wc0 = (const float*)d_in[5];
    const float* bc0 = (const float*)d_in[6];
    const float* wb1 = (const float*)d_in[7];
    const float* bb1 = (const float*)d_in[8];
    const float* wb2 = (const float*)d_in[9];
    const float* bb2 = (const float*)d_in[10];
    const float* wc1 = (const float*)d_in[11];
    const float* bc1 = (const float*)d_in[12];
    const float* w3  = (const float*)d_in[13];
    const float* b3  = (const float*)d_in[14];

    unsigned short* u = (unsigned short*)d_ws;
    // ws (ushort offsets), peak 157,286,400 B:
    //   h0p [n][4][25600][64] @0..52.4M (dead after conv1_fused)
    //   ycl [n][25600][128]   @52,428,800
    //   b1cl @26,214,400 ; bcl @39,321,600 ; h2p @0 ; w3a @26,214,400
    unsigned short* h0p  = u;
    unsigned short* ycl  = u + 52428800L;
    unsigned short* b1cl = u + 26214400L;
    unsigned short* bcl  = u + 39321600L;
    unsigned short* h2p  = u;
    unsigned short* w3a  = u + 26214400L;

    // small-conv frag arena lives in d_out (conv3_one overwrites all of d_out)
    unsigned short* wsa = (unsigned short*)d_out;
    unsigned short* a_conv1 = wsa;
    unsigned short* a_wc0   = wsa + 36 * 1024;
    unsigned short* a_wb1   = wsa + 44 * 1024;
    unsigned short* a_wb2   = wsa + 62 * 1024;
    unsigned short* a_wc1   = wsa + 80 * 1024;

    prep_small<<<dim3(24, 1, 1), dim3(256, 1, 1), 0, stream>>>(
        w1, wc0, wb1, wb2, wc1, w0, wsa);

    conv0_mfma<<<dim3(100, 4, 8), dim3(512, 1, 1), 0, stream>>>(x, wsa, b0, h0p);

    conv1_fused<<<dim3(100, 1, 8), dim3(512, 1, 1), 0, stream>>>(
        h0p, a_conv1, a_wc0, b1, bc0, ycl);

    wb3x3<false><<<dim3(100, 1, 8), dim3(512, 1, 1), 0, stream>>>(
        ycl, 128, 8, a_wb1, bb1, b1cl, nullptr);

    wb3x3<true><<<dim3(100, 1, 8), dim3(512, 1, 1), 0, stream>>>(
        b1cl, 64, 0, a_wb2, bb2, bcl, ycl);

    prep_w3<<<dim3(36, 1, 1), dim3(256, 1, 1), 0, stream>>>(w3, w3a);

    wc1x1<4, 2, true><<<dim3(50, 1, 8), dim3(512, 1, 1), 0, stream>>>(
        ycl, 128, bcl, 64, a_wc1, bc1, h2p);

    conv3_one<<<dim3(50, 2, 8), dim3(512, 1, 1), 0, stream>>>(h2p, w3a, b3, (float*)d_out);
}

// Round 10
// 290.316 us; speedup vs baseline: 1.8938x; 1.8938x over previous
//
#include <hip/hip_runtime.h>
#include <hip/hip_bf16.h>

typedef __attribute__((ext_vector_type(8))) short short8;
typedef __attribute__((ext_vector_type(16))) float f32x16;
typedef __attribute__((ext_vector_type(4))) float f32x4;
typedef __attribute__((ext_vector_type(4))) unsigned int uint4v;
typedef __attribute__((ext_vector_type(4))) unsigned short ushort4v;

__device__ __forceinline__ float silu_f(float v) {
    return v * __builtin_amdgcn_rcpf(1.0f + __expf(-v));
}
__device__ __forceinline__ unsigned short bfhi(float v) {
    __hip_bfloat16 h = __float2bfloat16(v);
    return *reinterpret_cast<unsigned short*>(&h);
}
__device__ __forceinline__ float bf2f(unsigned short u) {
    __hip_bfloat16 h;
    *reinterpret_cast<unsigned short*>(&h) = u;
    return __bfloat162float(h);
}

// ======= weight prep: f32 -> bf16 hi/lo fragments (pf*1024 + lane*8, lo +512)
// arena (in d_out): conv1 @0 (36pf), wc0 @36 (8pf), wb1 @44 (18pf),
//   wb2 @62 (18pf), wc1 @80 (12pf), w0 @92 (2pf; K=32 padded from 27). 94 pf.
__global__ __launch_bounds__(256) void prep_small(
    const float* __restrict__ w1, const float* __restrict__ wc0,
    const float* __restrict__ wb1, const float* __restrict__ wb2,
    const float* __restrict__ wc1, const float* __restrict__ w0,
    unsigned short* __restrict__ arena)
{
    const int u = blockIdx.x * 256 + threadIdx.x;   // 0..6015
    if (u >= 6016) return;
    const int lane = u & 63, pf = u >> 6;
    float wv[8];
    if (pf < 36) {
        const int q = pf, cc = q & 1, rnd = (q >> 1) & 1, tap = q >> 2;
        const int co = cc * 32 + (lane & 31), ci0 = rnd * 16 + (lane >> 5) * 8;
        #pragma unroll
        for (int j = 0; j < 8; ++j) wv[j] = w1[(co * 32 + ci0 + j) * 9 + tap];
    } else if (pf < 44) {
        const int q = pf - 36, cc = q & 1, rnd = q >> 1;
        const int co = cc * 32 + (lane & 31), ci0 = rnd * 16 + (lane >> 5) * 8;
        #pragma unroll
        for (int j = 0; j < 8; ++j) wv[j] = wc0[co * 64 + ci0 + j];
    } else if (pf < 62) {
        const int q = pf - 44, rnd = q & 1, tap = q >> 1;
        const int co = lane & 31, ci0 = rnd * 16 + (lane >> 5) * 8;
        #pragma unroll
        for (int j = 0; j < 8; ++j) wv[j] = wb1[(co * 32 + ci0 + j) * 9 + tap];
    } else if (pf < 80) {
        const int q = pf - 62, rnd = q & 1, tap = q >> 1;
        const int co = lane & 31, ci0 = rnd * 16 + (lane >> 5) * 8;
        #pragma unroll
        for (int j = 0; j < 8; ++j) wv[j] = wb2[(co * 32 + ci0 + j) * 9 + tap];
    } else if (pf < 92) {
        const int q = pf - 80, cc = q & 1, rnd = q >> 1;
        const int co = cc * 32 + (lane & 31), ci0 = rnd * 16 + (lane >> 5) * 8;
        #pragma unroll
        for (int j = 0; j < 8; ++j) wv[j] = wc1[co * 96 + ci0 + j];
    } else {
        const int co = lane & 31;
        const int k0 = (pf - 92) * 16 + (lane >> 5) * 8;
        #pragma unroll
        for (int j = 0; j < 8; ++j) {
            const int k = k0 + j;
            wv[j] = (k < 27) ? w0[(co * 3 + k / 9) * 9 + (k % 9)] : 0.0f;
        }
    }
    unsigned short hs[8], ls[8];
    #pragma unroll
    for (int j = 0; j < 8; ++j) {
        unsigned short hh = bfhi(wv[j]);
        hs[j] = hh; ls[j] = bfhi(wv[j] - bf2f(hh));
    }
    *reinterpret_cast<short8*>(&arena[pf * 1024 + lane * 8])       = *(short8*)hs;
    *reinterpret_cast<short8*>(&arena[pf * 1024 + 512 + lane * 8]) = *(short8*)ls;
}

// arena2 (in ws): w3, pf = ((cg*9+tap)*4 + PHASE*2+rnd)*2+cc, 144 pf
__global__ __launch_bounds__(256) void prep_w3(
    const float* __restrict__ w3, unsigned short* __restrict__ arena)
{
    const int u = blockIdx.x * 256 + threadIdx.x;   // 0..9215
    const int lane = u & 63, pf = u >> 6;
    const int cc = pf & 1, rnd2 = (pf >> 1) & 3, t9 = pf >> 3;
    const int tap = t9 % 9, cg = t9 / 9;
    const int co = cg * 64 + cc * 32 + (lane & 31);
    const int ci0 = (rnd2 >> 1) * 32 + (rnd2 & 1) * 16 + (lane >> 5) * 8;
    unsigned short hs[8], ls[8];
    #pragma unroll
    for (int j = 0; j < 8; ++j) {
        float wv = w3[(co * 64 + ci0 + j) * 9 + tap];
        unsigned short hh = bfhi(wv);
        hs[j] = hh; ls[j] = bfhi(wv - bf2f(hh));
    }
    *reinterpret_cast<short8*>(&arena[pf * 1024 + lane * 8])       = *(short8*)hs;
    *reinterpret_cast<short8*>(&arena[pf * 1024 + 512 + lane * 8]) = *(short8*)ls;
}

// ============ conv0: 3->32 s2 as K=32 gather-GEMM (MFMA), parity out ========
__global__ __launch_bounds__(512, 4) void conv0_mfma(
    const float* __restrict__ x, const unsigned short* __restrict__ wfr,
    const float* __restrict__ bias, unsigned short* __restrict__ out)
{
    const int tid = threadIdx.x;
    const int wv = tid >> 6, lane = tid & 63;
    const int p = lane & 31, h = lane >> 5;
    const int plane = blockIdx.y;
    const int pyp = plane >> 1, pxp = plane & 1;
    const int pp = blockIdx.x * 256 + wv * 32 + p;
    const int n = blockIdx.z;
    const int Y = 2 * (pp / 160) + pyp, X = 2 * (pp % 160) + pxp;

    int off[16]; float msk[16];
    #pragma unroll
    for (int rnd = 0; rnd < 2; ++rnd)
        #pragma unroll
        for (int j = 0; j < 8; ++j) {
            const int kidx = rnd * 16 + h * 8 + j;
            const int idx = rnd * 8 + j;
            if (kidx < 27) {
                const int ci = kidx / 9, tap = kidx - ci * 9;
                const int iy = 2 * Y + (tap / 3) - 1;
                const int ix = 2 * X + (tap % 3) - 1;
                const bool ok = (iy >= 0) && (iy < 640) && (ix >= 0) && (ix < 640);
                const int cy = min(max(iy, 0), 639), cx = min(max(ix, 0), 639);
                off[idx] = ci * 409600 + cy * 640 + cx;
                msk[idx] = ok ? 1.0f : 0.0f;
            } else {
                off[idx] = 0; msk[idx] = 0.0f;
            }
        }

    f32x16 acc;
    #pragma unroll
    for (int q = 0; q < 4; ++q) {
        f32x4 b4 = *reinterpret_cast<const f32x4*>(&bias[q * 8 + 4 * h]);
        #pragma unroll
        for (int r = 0; r < 4; ++r) acc[q * 4 + r] = b4[r];
    }

    const float* xb = x + (long)n * 1228800;
    #pragma unroll
    for (int rnd = 0; rnd < 2; ++rnd) {
        unsigned short hs[8], ls[8];
        #pragma unroll
        for (int j = 0; j < 8; ++j) {
            float v = xb[off[rnd * 8 + j]] * msk[rnd * 8 + j];
            unsigned short hh = bfhi(v);
            hs[j] = hh; ls[j] = bfhi(v - bf2f(hh));
        }
        short8 Bh = *(short8*)hs, Bl = *(short8*)ls;
        const unsigned short* fb = wfr + (92 + rnd) * 1024 + lane * 8;
        short8 Awh = *reinterpret_cast<const short8*>(fb);
        short8 Awl = *reinterpret_cast<const short8*>(fb + 512);
        acc = __builtin_amdgcn_mfma_f32_32x32x16_bf16(Awh, Bh, acc, 0, 0, 0);
        acc = __builtin_amdgcn_mfma_f32_32x32x16_bf16(Awh, Bl, acc, 0, 0, 0);
        acc = __builtin_amdgcn_mfma_f32_32x32x16_bf16(Awl, Bh, acc, 0, 0, 0);
    }

    unsigned short* op = out + (((long)n * 4 + plane) * 25600 + pp) * 64;
    #pragma unroll
    for (int q = 0; q < 4; ++q) {
        ushort4v hv, lv;
        #pragma unroll
        for (int r = 0; r < 4; ++r) {
            float v = silu_f(acc[q * 4 + r]);
            unsigned short hh = bfhi(v);
            hv[r] = hh; lv[r] = bfhi(v - bf2f(hh));
        }
        *reinterpret_cast<ushort4v*>(op + q * 16 + 4 * h)     = hv;
        *reinterpret_cast<ushort4v*>(op + q * 16 + 8 + 4 * h) = lv;
    }
}

// ============ conv1: 32->64 s2 3x3 + FUSED wc0 — cc-split waves =============
// 256 threads = 4 waves = (2 rows) x (2 cc-chunks). Tile 32x2 out px.
// Accum/thread: 16 (conv1) + 16 (wc0) AGPR. LDS: 325 recs x 64B = 20.8 KB.
__global__ __launch_bounds__(256, 4) void conv1_fused(
    const unsigned short* __restrict__ h0, const unsigned short* __restrict__ wfr,
    const unsigned short* __restrict__ wc0fr, const float* __restrict__ bias,
    const float* __restrict__ bc0, unsigned short* __restrict__ ycl)
{
    __shared__ unsigned short lds[10400];        // max(325*32, 64*128) ush
    const int tid = threadIdx.x;
    const int wv = tid >> 6, lane = tid & 63;
    const int p = lane & 31, h = lane >> 5;
    const int r = wv >> 1, cc = wv & 1;          // wave = (row, cc-chunk)
    const int bx = blockIdx.x % 5, by = blockIdx.x / 5;
    const int ox0 = bx * 32, oy0 = by * 2;
    const int n = blockIdx.z;

    f32x16 acc;
    #pragma unroll
    for (int q = 0; q < 4; ++q) {
        f32x4 b4 = *reinterpret_cast<const f32x4*>(&bias[cc * 32 + q * 8 + 4 * h]);
        #pragma unroll
        for (int r2 = 0; r2 < 4; ++r2) acc[q * 4 + r2] = b4[r2];
    }

    // K-loop: 2 rounds (ci halves), parity tiles:
    //   ee[0,64)W32(2r), eo[64,130)W33(2r), oe[130,226)W32(3r), oo[226,325)W33(3r)
    for (int c = 0; c < 2; ++c) {
        __syncthreads();
        for (int u = tid; u < 1300; u += 256) {
            const int rec = u >> 2, s = u & 3;
            int gp, row, col;
            if (rec < 64)       { gp = 0; row = rec >> 5;  col = rec & 31; }
            else if (rec < 130) { gp = 1; int r2 = rec - 64;  row = r2 / 33; col = r2 - row * 33; }
            else if (rec < 226) { gp = 2; int r2 = rec - 130; row = r2 >> 5; col = r2 & 31; }
            else                { gp = 3; int r2 = rec - 226; row = r2 / 33; col = r2 - row * 33; }
            const int gr = (gp >= 2) ? oy0 - 1 + row : oy0 + row;
            const int gc = (gp & 1)  ? ox0 - 1 + col : ox0 + col;
            uint4v val = {0, 0, 0, 0};
            if (gr >= 0 && gr < 160 && gc >= 0 && gc < 160)
                val = *reinterpret_cast<const uint4v*>(
                    h0 + (((long)n * 4 + gp) * 25600 + gr * 160 + gc) * 64 + (4 * c + s) * 8);
            *reinterpret_cast<uint4v*>(&lds[rec * 32 + ((s ^ (rec & 3)) * 8)]) = val;
        }
        __syncthreads();

        #pragma unroll
        for (int tap = 0; tap < 9; ++tap) {
            const int dy = tap / 3 - 1, dx = tap % 3 - 1;
            const int ppy = dy & 1, ppx = dx & 1;
            const int toy = ppy ? ((dy == -1) ? 0 : 1) : 0;
            const int tox = ppx ? ((dx == -1) ? 0 : 1) : 0;
            const int gp = ppy * 2 + ppx;
            const int base = (gp == 0) ? 0 : (gp == 1) ? 64 : (gp == 2) ? 130 : 226;
            const int W = ppx ? 33 : 32;
            const int rec = base + (ppy ? (r + toy) : r) * W + (p + tox);
            const unsigned short* t = &lds[rec * 32];
            short8 Bh = *reinterpret_cast<const short8*>(t + (((2 * h)     ^ (rec & 3)) * 8));
            short8 Bl = *reinterpret_cast<const short8*>(t + (((2 * h + 1) ^ (rec & 3)) * 8));
            const unsigned short* fb = wfr + ((tap * 2 + c) * 2 + cc) * 1024 + lane * 8;
            short8 Awh = *reinterpret_cast<const short8*>(fb);
            short8 Awl = *reinterpret_cast<const short8*>(fb + 512);
            acc = __builtin_amdgcn_mfma_f32_32x32x16_bf16(Awh, Bh, acc, 0, 0, 0);
            acc = __builtin_amdgcn_mfma_f32_32x32x16_bf16(Awh, Bl, acc, 0, 0, 0);
            acc = __builtin_amdgcn_mfma_f32_32x32x16_bf16(Awl, Bh, acc, 0, 0, 0);
        }
    }

    // ---- stage y = silu(conv1) to LDS: 64 recs x 128 ush, slot-XOR swizzle
    __syncthreads();
    {
        const int rec2 = r * 32 + p;
        #pragma unroll
        for (int q = 0; q < 4; ++q) {
            ushort4v hv, lv;
            #pragma unroll
            for (int r2 = 0; r2 < 4; ++r2) {
                float v = silu_f(acc[q * 4 + r2]);
                unsigned short hh = bfhi(v);
                hv[r2] = hh; lv[r2] = bfhi(v - bf2f(hh));
            }
            const int lsh = (2 * (cc * 4 + q))     ^ (rec2 & 15);
            const int lsl = (2 * (cc * 4 + q) + 1) ^ (rec2 & 15);
            *reinterpret_cast<ushort4v*>(&lds[rec2 * 128 + lsh * 8 + 4 * h]) = hv;
            *reinterpret_cast<ushort4v*>(&lds[rec2 * 128 + lsl * 8 + 4 * h]) = lv;
        }
    }
    __syncthreads();

    // ---- wc0: 1x1 64->64 from LDS y-tile; wave owns cc output chunk
    f32x16 a2;
    #pragma unroll
    for (int q = 0; q < 4; ++q) {
        f32x4 b4 = *reinterpret_cast<const f32x4*>(&bc0[cc * 32 + q * 8 + 4 * h]);
        #pragma unroll
        for (int r2 = 0; r2 < 4; ++r2) a2[q * 4 + r2] = b4[r2];
    }
    {
        const int rec2 = r * 32 + p;
        #pragma unroll
        for (int rnd = 0; rnd < 4; ++rnd) {
            const int sh = (4 * rnd + 2 * h)     ^ (rec2 & 15);
            const int sl = (4 * rnd + 2 * h + 1) ^ (rec2 & 15);
            short8 Bh = *reinterpret_cast<const short8*>(&lds[rec2 * 128 + sh * 8]);
            short8 Bl = *reinterpret_cast<const short8*>(&lds[rec2 * 128 + sl * 8]);
            const unsigned short* fb = wc0fr + (rnd * 2 + cc) * 1024 + lane * 8;
            short8 Awh = *reinterpret_cast<const short8*>(fb);
            short8 Awl = *reinterpret_cast<const short8*>(fb + 512);
            a2 = __builtin_amdgcn_mfma_f32_32x32x16_bf16(Awh, Bh, a2, 0, 0, 0);
            a2 = __builtin_amdgcn_mfma_f32_32x32x16_bf16(Awh, Bl, a2, 0, 0, 0);
            a2 = __builtin_amdgcn_mfma_f32_32x32x16_bf16(Awl, Bh, a2, 0, 0, 0);
        }
    }

    const int oy = oy0 + r;
    unsigned short* op = ycl + ((long)n * 25600 + (long)oy * 160 + ox0 + p) * 128;
    #pragma unroll
    for (int q = 0; q < 4; ++q) {
        ushort4v hv, lv;
        #pragma unroll
        for (int r2 = 0; r2 < 4; ++r2) {
            float v = silu_f(a2[q * 4 + r2]);
            unsigned short hh = bfhi(v);
            hv[r2] = hh; lv[r2] = bfhi(v - bf2f(hh));
        }
        const int gq = cc * 4 + q;
        *reinterpret_cast<ushort4v*>(op + gq * 16 + 4 * h)     = hv;
        *reinterpret_cast<ushort4v*>(op + gq * 16 + 8 + 4 * h) = lv;
    }
}

// ============ wb: 32->32 s1 3x3, tile-only LDS, frags from global ===========
template <bool RESID>
__global__ __launch_bounds__(512, 4) void wb3x3(
    const unsigned short* __restrict__ in, int inRec, int inSlot0,
    const unsigned short* __restrict__ wfr, const float* __restrict__ bias,
    unsigned short* __restrict__ outb, const unsigned short* __restrict__ resid)
{
    __shared__ unsigned short lds[21760];        // tile 34x10 x 64 ush (43.5 KB)
    const int tid = threadIdx.x;
    const int wv = tid >> 6, lane = tid & 63;
    const int p = lane & 31, h = lane >> 5;
    const int bx = blockIdx.x % 5, by = blockIdx.x / 5;
    const int ox0 = bx * 32, oy0 = by * 8;
    const int n = blockIdx.z;

    for (int u = tid; u < 2720; u += 512) {      // tile 34x10, 8 slots/rec
        const int rec = u >> 3, s = u & 7;
        const int row = rec / 34, col = rec - row * 34;
        const int gr = oy0 - 1 + row, gc = ox0 - 1 + col;
        uint4v val = {0, 0, 0, 0};
        if (gr >= 0 && gr < 160 && gc >= 0 && gc < 160)
            val = *reinterpret_cast<const uint4v*>(
                in + ((long)n * 25600 + gr * 160 + gc) * inRec + (inSlot0 + s) * 8);
        *reinterpret_cast<uint4v*>(&lds[rec * 64 + ((s ^ (rec & 7)) * 8)]) = val;
    }

    f32x16 acc;
    #pragma unroll
    for (int q = 0; q < 4; ++q) {
        f32x4 b4 = *reinterpret_cast<const f32x4*>(&bias[q * 8 + 4 * h]);
        #pragma unroll
        for (int r = 0; r < 4; ++r) acc[q * 4 + r] = b4[r];
    }
    __syncthreads();

    #pragma unroll
    for (int tap = 0; tap < 9; ++tap) {
        const int dy = tap / 3 - 1, dx = tap % 3 - 1;
        const int rec = (wv + dy + 1) * 34 + (p + dx + 1);
        const unsigned short* t = &lds[rec * 64];
        short8 Bh[2], Bl[2];
        #pragma unroll
        for (int rnd = 0; rnd < 2; ++rnd) {
            Bh[rnd] = *reinterpret_cast<const short8*>(t + (((rnd*4 + 2*h)     ^ (rec & 7)) * 8));
            Bl[rnd] = *reinterpret_cast<const short8*>(t + (((rnd*4 + 2*h + 1) ^ (rec & 7)) * 8));
        }
        #pragma unroll
        for (int rnd = 0; rnd < 2; ++rnd) {
            const unsigned short* fb = wfr + (tap * 2 + rnd) * 1024 + lane * 8;
            short8 Awh = *reinterpret_cast<const short8*>(fb);
            short8 Awl = *reinterpret_cast<const short8*>(fb + 512);
            acc = __builtin_amdgcn_mfma_f32_32x32x16_bf16(Awh, Bh[rnd], acc, 0, 0, 0);
            acc = __builtin_amdgcn_mfma_f32_32x32x16_bf16(Awh, Bl[rnd], acc, 0, 0, 0);
            acc = __builtin_amdgcn_mfma_f32_32x32x16_bf16(Awl, Bh[rnd], acc, 0, 0, 0);
        }
    }

    const int oy = oy0 + wv;
    const long prow = (long)n * 25600 + (long)oy * 160 + ox0 + p;
    unsigned short* op = outb + prow * 64;
    const unsigned short* rp = RESID ? resid + prow * 128 : nullptr;
    #pragma unroll
    for (int q = 0; q < 4; ++q) {
        ushort4v hv, lv;
        float vs[4];
        #pragma unroll
        for (int r = 0; r < 4; ++r) vs[r] = silu_f(acc[q * 4 + r]);
        if (RESID) {
            ushort4v rh = *reinterpret_cast<const ushort4v*>(rp + (q + 4) * 16 + 4 * h);
            ushort4v rl = *reinterpret_cast<const ushort4v*>(rp + (q + 4) * 16 + 8 + 4 * h);
            #pragma unroll
            for (int r = 0; r < 4; ++r) vs[r] += bf2f(rh[r]) + bf2f(rl[r]);
        }
        #pragma unroll
        for (int r = 0; r < 4; ++r) {
            unsigned short hh = bfhi(vs[r]);
            hv[r] = hh; lv[r] = bfhi(vs[r] - bf2f(hh));
        }
        *reinterpret_cast<ushort4v*>(op + q * 16 + 4 * h)     = hv;
        *reinterpret_cast<ushort4v*>(op + q * 16 + 8 + 4 * h) = lv;
    }
}

// ============ wc1: 1x1 concat(96->64), zero LDS, frags from global ==========
template <int R1, int R2, bool POUT>
__global__ __launch_bounds__(512, 4) void wc1x1(
    const unsigned short* __restrict__ in1, int rec1,
    const unsigned short* __restrict__ in2, int rec2,
    const unsigned short* __restrict__ wfr, const float* __restrict__ bias,
    unsigned short* __restrict__ outb)
{
    constexpr int RT = R1 + R2;
    const int tid = threadIdx.x;
    const int wv = tid >> 6, lane = tid & 63;
    const int p = lane & 31, h = lane >> 5;
    const int n = blockIdx.z;
    const int px0 = blockIdx.x * 512;

    f32x16 acc[2][2];
    #pragma unroll
    for (int cc = 0; cc < 2; ++cc)
        #pragma unroll
        for (int q = 0; q < 4; ++q) {
            f32x4 b4 = *reinterpret_cast<const f32x4*>(&bias[cc * 32 + q * 8 + 4 * h]);
            #pragma unroll
            for (int r = 0; r < 4; ++r) { acc[cc][0][q*4+r] = b4[r]; acc[cc][1][q*4+r] = b4[r]; }
        }

    #pragma unroll
    for (int rnd = 0; rnd < RT; ++rnd) {
        const unsigned short* bp = (rnd < R1) ? in1 : in2;
        const int recN = (rnd < R1) ? rec1 : rec2;
        const int s0 = 4 * ((rnd < R1) ? rnd : rnd - R1);
        #pragma unroll
        for (int k = 0; k < 2; ++k) {
            const int px = px0 + (wv * 2 + k) * 32 + p;
            const unsigned short* sp = bp + ((long)n * 25600 + px) * recN + (s0 + 2 * h) * 8;
            short8 Bh = *reinterpret_cast<const short8*>(sp);
            short8 Bl = *reinterpret_cast<const short8*>(sp + 8);
            #pragma unroll
            for (int cc = 0; cc < 2; ++cc) {
                const unsigned short* fb = wfr + (rnd * 2 + cc) * 1024 + lane * 8;
                short8 Awh = *reinterpret_cast<const short8*>(fb);
                short8 Awl = *reinterpret_cast<const short8*>(fb + 512);
                acc[cc][k] = __builtin_amdgcn_mfma_f32_32x32x16_bf16(Awh, Bh, acc[cc][k], 0, 0, 0);
                acc[cc][k] = __builtin_amdgcn_mfma_f32_32x32x16_bf16(Awh, Bl, acc[cc][k], 0, 0, 0);
                acc[cc][k] = __builtin_amdgcn_mfma_f32_32x32x16_bf16(Awl, Bh, acc[cc][k], 0, 0, 0);
            }
        }
    }

    #pragma unroll
    for (int k = 0; k < 2; ++k) {
        const int px = px0 + (wv * 2 + k) * 32 + p;
        unsigned short* op;
        if (POUT) {
            const int y = px / 160, xx = px % 160;
            const int pl = (y & 1) * 2 + (xx & 1);
            op = outb + (((long)n * 4 + pl) * 6400 + (y >> 1) * 80 + (xx >> 1)) * 128;
        } else {
            op = outb + ((long)n * 25600 + px) * 128;
        }
        #pragma unroll
        for (int cc = 0; cc < 2; ++cc)
            #pragma unroll
            for (int q = 0; q < 4; ++q) {
                ushort4v hv, lv;
                #pragma unroll
                for (int r = 0; r < 4; ++r) {
                    float v = silu_f(acc[cc][k][q * 4 + r]);
                    unsigned short hh = bfhi(v);
                    hv[r] = hh; lv[r] = bfhi(v - bf2f(hh));
                }
                const int gq = cc * 4 + q;
                *reinterpret_cast<ushort4v*>(op + gq * 16 + 4 * h)     = hv;
                *reinterpret_cast<ushort4v*>(op + gq * 16 + 8 + 4 * h) = lv;
            }
    }
}

// ============ conv3: 64->128 s2 3x3, tile-only LDS, frags from global =======
template <int PHASE>
__global__ __launch_bounds__(512, 4) void conv3_par(
    const unsigned short* __restrict__ h2p, const unsigned short* __restrict__ wfr,
    const float* __restrict__ bias, float* __restrict__ outf)
{
    __shared__ unsigned short lds[34848];        // tile 1089 x 32 ush (69.7 KB)
    const int tid = threadIdx.x;
    const int wv = tid >> 6, lane = tid & 63;
    const int p = lane & 31, h = lane >> 5;
    const int bx = blockIdx.x % 5, by = blockIdx.x / 5;
    const int ox0 = bx * 16, oy0 = by * 16;
    const int cg = blockIdx.y;
    const int co0 = cg * 64;
    const int n = blockIdx.z;

    f32x16 acc[2];
    #pragma unroll
    for (int cc = 0; cc < 2; ++cc)
        #pragma unroll
        for (int q = 0; q < 4; ++q) {
            f32x4 b4 = {0.f, 0.f, 0.f, 0.f};
            if (PHASE == 0)
                b4 = *reinterpret_cast<const f32x4*>(&bias[co0 + cc * 32 + q * 8 + 4 * h]);
            #pragma unroll
            for (int r = 0; r < 4; ++r) acc[cc][q * 4 + r] = b4[r];
        }

    for (int rnd = 0; rnd < 2; ++rnd) {
        __syncthreads();
        for (int u = tid; u < 4356; u += 512) {
            const int rec = u >> 2, s = u & 3;
            int gp, row, col;
            if (rec < 256)      { gp = 0; row = rec >> 4; col = rec & 15; }
            else if (rec < 528) { gp = 1; int r2 = rec - 256; row = r2 / 17; col = r2 - row * 17; }
            else if (rec < 800) { gp = 2; int r2 = rec - 528; row = r2 >> 4; col = r2 & 15; }
            else                { gp = 3; int r2 = rec - 800; row = r2 / 17; col = r2 - row * 17; }
            const int gr = (gp >= 2) ? oy0 - 1 + row : oy0 + row;
            const int gc = (gp & 1)  ? ox0 - 1 + col : ox0 + col;
            uint4v val = {0, 0, 0, 0};
            if (gr >= 0 && gr < 80 && gc >= 0 && gc < 80)
                val = *reinterpret_cast<const uint4v*>(
                    h2p + (((long)n * 4 + gp) * 6400 + gr * 80 + gc) * 128 + (PHASE * 8 + rnd * 4 + s) * 8);
            *reinterpret_cast<uint4v*>(&lds[rec * 32 + ((s ^ (rec & 3)) * 8)]) = val;
        }
        __syncthreads();

        #pragma unroll
        for (int tap = 0; tap < 9; ++tap) {
            const int dy = tap / 3 - 1, dx = tap % 3 - 1;
            const int ppy = dy & 1, ppx = dx & 1;
            const int toy = ppy ? ((dy == -1) ? 0 : 1) : 0;
            const int tox = ppx ? ((dx == -1) ? 0 : 1) : 0;
            const int gp = ppy * 2 + ppx;
            const int base = (gp == 0) ? 0 : (gp == 1) ? 256 : (gp == 2) ? 528 : 800;
            const int W = ppx ? 17 : 16;
            const int rl = wv * 2 + (p >> 4), cl = p & 15;
            const int rec = base + (ppy ? (rl + toy) : rl) * W + (cl + tox);
            const unsigned short* t = &lds[rec * 32];
            short8 Bh = *reinterpret_cast<const short8*>(t + (((2*h)     ^ (rec & 3)) * 8));
            short8 Bl = *reinterpret_cast<const short8*>(t + (((2*h + 1) ^ (rec & 3)) * 8));
            #pragma unroll
            for (int cc = 0; cc < 2; ++cc) {
                const unsigned short* fb =
                    wfr + (((cg * 9 + tap) * 4 + PHASE * 2 + rnd) * 2 + cc) * 1024 + lane * 8;
                short8 Awh = *reinterpret_cast<const short8*>(fb);
                short8 Awl = *reinterpret_cast<const short8*>(fb + 512);
                acc[cc] = __builtin_amdgcn_mfma_f32_32x32x16_bf16(Awh, Bh, acc[cc], 0, 0, 0);
                acc[cc] = __builtin_amdgcn_mfma_f32_32x32x16_bf16(Awh, Bl, acc[cc], 0, 0, 0);
                acc[cc] = __builtin_amdgcn_mfma_f32_32x32x16_bf16(Awl, Bh, acc[cc], 0, 0, 0);
            }
        }
    }

    const int rl = wv * 2 + (p >> 4);
    const int oy = oy0 + rl;
    const int pxg = oy * 80 + ox0 + (p & 15);
    #pragma unroll
    for (int cc = 0; cc < 2; ++cc)
        #pragma unroll
        for (int q = 0; q < 4; ++q)
            #pragma unroll
            for (int r = 0; r < 4; ++r) {
                const int co = co0 + cc * 32 + q * 8 + 4 * h + r;
                const long idx = ((long)n * 128 + co) * 6400 + pxg;
                if (PHASE == 0) {
                    outf[idx] = acc[cc][q * 4 + r];
                } else {
                    outf[idx] = silu_f(outf[idx] + acc[cc][q * 4 + r]);
                }
            }
}

extern "C" void kernel_launch(void* const* d_in, const int* in_sizes, int n_in,
                              void* d_out, int out_size, void* d_ws, size_t ws_size,
                              hipStream_t stream) {
    const float* x   = (const float*)d_in[0];
    const float* w0  = (const float*)d_in[1];
    const float* b0  = (const float*)d_in[2];
    const float* w1  = (const float*)d_in[3];
    const float* b1  = (const float*)d_in[4];
    const float* wc0 = (const float*)d_in[5];
    const float* bc0 = (const float*)d_in[6];
    const float* wb1 = (const float*)d_in[7];
    const float* bb1 = (const float*)d_in[8];
    const float* wb2 = (const float*)d_in[9];
    const float* bb2 = (const float*)d_in[10];
    const float* wc1 = (const float*)d_in[11];
    const float* bc1 = (const float*)d_in[12];
    const float* w3  = (const float*)d_in[13];
    const float* b3  = (const float*)d_in[14];

    unsigned short* u = (unsigned short*)d_ws;
    // ws (ushort offsets), peak 157,286,400 B:
    //   h0p [n][4][25600][64] @0..52.4M (dead after conv1_fused)
    //   ycl [n][25600][128]   @52,428,800
    //   b1cl @26,214,400 ; bcl @39,321,600 ; h2p @0 ; w3a @26,214,400
    unsigned short* h0p  = u;
    unsigned short* ycl  = u + 52428800L;
    unsigned short* b1cl = u + 26214400L;
    unsigned short* bcl  = u + 39321600L;
    unsigned short* h2p  = u;
    unsigned short* w3a  = u + 26214400L;

    // small-conv frag arena lives in d_out (conv3 overwrites all of d_out)
    unsigned short* wsa = (unsigned short*)d_out;
    unsigned short* a_conv1 = wsa;
    unsigned short* a_wc0   = wsa + 36 * 1024;
    unsigned short* a_wb1   = wsa + 44 * 1024;
    unsigned short* a_wb2   = wsa + 62 * 1024;
    unsigned short* a_wc1   = wsa + 80 * 1024;

    prep_small<<<dim3(24, 1, 1), dim3(256, 1, 1), 0, stream>>>(
        w1, wc0, wb1, wb2, wc1, w0, wsa);

    conv0_mfma<<<dim3(100, 4, 8), dim3(512, 1, 1), 0, stream>>>(x, wsa, b0, h0p);

    // conv1+wc0 fused: 400 tiles (5 bx x 80 by) x 8 n, 256-thread blocks
    conv1_fused<<<dim3(400, 1, 8), dim3(256, 1, 1), 0, stream>>>(
        h0p, a_conv1, a_wc0, b1, bc0, ycl);

    wb3x3<false><<<dim3(100, 1, 8), dim3(512, 1, 1), 0, stream>>>(
        ycl, 128, 8, a_wb1, bb1, b1cl, nullptr);

    wb3x3<true><<<dim3(100, 1, 8), dim3(512, 1, 1), 0, stream>>>(
        b1cl, 64, 0, a_wb2, bb2, bcl, ycl);

    prep_w3<<<dim3(36, 1, 1), dim3(256, 1, 1), 0, stream>>>(w3, w3a);

    wc1x1<4, 2, true><<<dim3(50, 1, 8), dim3(512, 1, 1), 0, stream>>>(
        ycl, 128, bcl, 64, a_wc1, bc1, h2p);

    conv3_par<0><<<dim3(25, 2, 8), dim3(512, 1, 1), 0, stream>>>(h2p, w3a, b3, (float*)d_out);
    conv3_par<1><<<dim3(25, 2, 8), dim3(512, 1, 1), 0, stream>>>(h2p, w3a, b3, (float*)d_out);
}

// Round 11
// 275.409 us; speedup vs baseline: 1.9963x; 1.0541x over previous
//
#include <hip/hip_runtime.h>
#include <hip/hip_bf16.h>

typedef __attribute__((ext_vector_type(8))) short short8;
typedef __attribute__((ext_vector_type(16))) float f32x16;
typedef __attribute__((ext_vector_type(4))) float f32x4;
typedef __attribute__((ext_vector_type(4))) unsigned int uint4v;
typedef __attribute__((ext_vector_type(4))) unsigned short ushort4v;

__device__ __forceinline__ float silu_f(float v) {
    return v * __builtin_amdgcn_rcpf(1.0f + __expf(-v));
}
__device__ __forceinline__ unsigned short bfhi(float v) {
    __hip_bfloat16 h = __float2bfloat16(v);
    return *reinterpret_cast<unsigned short*>(&h);
}
__device__ __forceinline__ float bf2f(unsigned short u) {
    __hip_bfloat16 h;
    *reinterpret_cast<unsigned short*>(&h) = u;
    return __bfloat162float(h);
}

// ======= weight prep: f32 -> bf16 hi/lo fragments (pf*1024 + lane*8, lo +512)
// arena (in d_out): conv1 @0 (36pf), wc0 @36 (8pf), wb1 @44 (18pf),
//   wb2 @62 (18pf), wc1 @80 (12pf), w0 @92 (2pf; K=32 padded from 27). 94 pf.
__global__ __launch_bounds__(256) void prep_small(
    const float* __restrict__ w1, const float* __restrict__ wc0,
    const float* __restrict__ wb1, const float* __restrict__ wb2,
    const float* __restrict__ wc1, const float* __restrict__ w0,
    unsigned short* __restrict__ arena)
{
    const int u = blockIdx.x * 256 + threadIdx.x;   // 0..6015
    if (u >= 6016) return;
    const int lane = u & 63, pf = u >> 6;
    float wv[8];
    if (pf < 36) {
        const int q = pf, cc = q & 1, rnd = (q >> 1) & 1, tap = q >> 2;
        const int co = cc * 32 + (lane & 31), ci0 = rnd * 16 + (lane >> 5) * 8;
        #pragma unroll
        for (int j = 0; j < 8; ++j) wv[j] = w1[(co * 32 + ci0 + j) * 9 + tap];
    } else if (pf < 44) {
        const int q = pf - 36, cc = q & 1, rnd = q >> 1;
        const int co = cc * 32 + (lane & 31), ci0 = rnd * 16 + (lane >> 5) * 8;
        #pragma unroll
        for (int j = 0; j < 8; ++j) wv[j] = wc0[co * 64 + ci0 + j];
    } else if (pf < 62) {
        const int q = pf - 44, rnd = q & 1, tap = q >> 1;
        const int co = lane & 31, ci0 = rnd * 16 + (lane >> 5) * 8;
        #pragma unroll
        for (int j = 0; j < 8; ++j) wv[j] = wb1[(co * 32 + ci0 + j) * 9 + tap];
    } else if (pf < 80) {
        const int q = pf - 62, rnd = q & 1, tap = q >> 1;
        const int co = lane & 31, ci0 = rnd * 16 + (lane >> 5) * 8;
        #pragma unroll
        for (int j = 0; j < 8; ++j) wv[j] = wb2[(co * 32 + ci0 + j) * 9 + tap];
    } else if (pf < 92) {
        const int q = pf - 80, cc = q & 1, rnd = q >> 1;
        const int co = cc * 32 + (lane & 31), ci0 = rnd * 16 + (lane >> 5) * 8;
        #pragma unroll
        for (int j = 0; j < 8; ++j) wv[j] = wc1[co * 96 + ci0 + j];
    } else {
        const int co = lane & 31;
        const int k0 = (pf - 92) * 16 + (lane >> 5) * 8;
        #pragma unroll
        for (int j = 0; j < 8; ++j) {
            const int k = k0 + j;
            wv[j] = (k < 27) ? w0[(co * 3 + k / 9) * 9 + (k % 9)] : 0.0f;
        }
    }
    unsigned short hs[8], ls[8];
    #pragma unroll
    for (int j = 0; j < 8; ++j) {
        unsigned short hh = bfhi(wv[j]);
        hs[j] = hh; ls[j] = bfhi(wv[j] - bf2f(hh));
    }
    *reinterpret_cast<short8*>(&arena[pf * 1024 + lane * 8])       = *(short8*)hs;
    *reinterpret_cast<short8*>(&arena[pf * 1024 + 512 + lane * 8]) = *(short8*)ls;
}

// arena2 (in ws): w3, pf = ((cg*9+tap)*4 + rr)*2+cc, rr = ci/16. 144 pf
__global__ __launch_bounds__(256) void prep_w3(
    const float* __restrict__ w3, unsigned short* __restrict__ arena)
{
    const int u = blockIdx.x * 256 + threadIdx.x;   // 0..9215
    const int lane = u & 63, pf = u >> 6;
    const int cc = pf & 1, rr = (pf >> 1) & 3, t9 = pf >> 3;
    const int tap = t9 % 9, cg = t9 / 9;
    const int co = cg * 64 + cc * 32 + (lane & 31);
    const int ci0 = rr * 16 + (lane >> 5) * 8;
    unsigned short hs[8], ls[8];
    #pragma unroll
    for (int j = 0; j < 8; ++j) {
        float wv = w3[(co * 64 + ci0 + j) * 9 + tap];
        unsigned short hh = bfhi(wv);
        hs[j] = hh; ls[j] = bfhi(wv - bf2f(hh));
    }
    *reinterpret_cast<short8*>(&arena[pf * 1024 + lane * 8])       = *(short8*)hs;
    *reinterpret_cast<short8*>(&arena[pf * 1024 + 512 + lane * 8]) = *(short8*)ls;
}

// ============ conv0: 3->32 s2 as K=32 gather-GEMM (MFMA), parity out ========
__global__ __launch_bounds__(512, 4) void conv0_mfma(
    const float* __restrict__ x, const unsigned short* __restrict__ wfr,
    const float* __restrict__ bias, unsigned short* __restrict__ out)
{
    const int tid = threadIdx.x;
    const int wv = tid >> 6, lane = tid & 63;
    const int p = lane & 31, h = lane >> 5;
    const int plane = blockIdx.y;
    const int pyp = plane >> 1, pxp = plane & 1;
    const int pp = blockIdx.x * 256 + wv * 32 + p;
    const int n = blockIdx.z;
    const int Y = 2 * (pp / 160) + pyp, X = 2 * (pp % 160) + pxp;

    int off[16]; float msk[16];
    #pragma unroll
    for (int rnd = 0; rnd < 2; ++rnd)
        #pragma unroll
        for (int j = 0; j < 8; ++j) {
            const int kidx = rnd * 16 + h * 8 + j;
            const int idx = rnd * 8 + j;
            if (kidx < 27) {
                const int ci = kidx / 9, tap = kidx - ci * 9;
                const int iy = 2 * Y + (tap / 3) - 1;
                const int ix = 2 * X + (tap % 3) - 1;
                const bool ok = (iy >= 0) && (iy < 640) && (ix >= 0) && (ix < 640);
                const int cy = min(max(iy, 0), 639), cx = min(max(ix, 0), 639);
                off[idx] = ci * 409600 + cy * 640 + cx;
                msk[idx] = ok ? 1.0f : 0.0f;
            } else {
                off[idx] = 0; msk[idx] = 0.0f;
            }
        }

    f32x16 acc;
    #pragma unroll
    for (int q = 0; q < 4; ++q) {
        f32x4 b4 = *reinterpret_cast<const f32x4*>(&bias[q * 8 + 4 * h]);
        #pragma unroll
        for (int r = 0; r < 4; ++r) acc[q * 4 + r] = b4[r];
    }

    const float* xb = x + (long)n * 1228800;
    #pragma unroll
    for (int rnd = 0; rnd < 2; ++rnd) {
        unsigned short hs[8], ls[8];
        #pragma unroll
        for (int j = 0; j < 8; ++j) {
            float v = xb[off[rnd * 8 + j]] * msk[rnd * 8 + j];
            unsigned short hh = bfhi(v);
            hs[j] = hh; ls[j] = bfhi(v - bf2f(hh));
        }
        short8 Bh = *(short8*)hs, Bl = *(short8*)ls;
        const unsigned short* fb = wfr + (92 + rnd) * 1024 + lane * 8;
        short8 Awh = *reinterpret_cast<const short8*>(fb);
        short8 Awl = *reinterpret_cast<const short8*>(fb + 512);
        acc = __builtin_amdgcn_mfma_f32_32x32x16_bf16(Awh, Bh, acc, 0, 0, 0);
        acc = __builtin_amdgcn_mfma_f32_32x32x16_bf16(Awh, Bl, acc, 0, 0, 0);
        acc = __builtin_amdgcn_mfma_f32_32x32x16_bf16(Awl, Bh, acc, 0, 0, 0);
    }

    unsigned short* op = out + (((long)n * 4 + plane) * 25600 + pp) * 64;
    #pragma unroll
    for (int q = 0; q < 4; ++q) {
        ushort4v hv, lv;
        #pragma unroll
        for (int r = 0; r < 4; ++r) {
            float v = silu_f(acc[q * 4 + r]);
            unsigned short hh = bfhi(v);
            hv[r] = hh; lv[r] = bfhi(v - bf2f(hh));
        }
        *reinterpret_cast<ushort4v*>(op + q * 16 + 4 * h)     = hv;
        *reinterpret_cast<ushort4v*>(op + q * 16 + 8 + 4 * h) = lv;
    }
}

// ============ conv1: 32->64 s2 3x3 + FUSED wc0 — cc-split waves =============
// 256 threads = 4 waves = (2 rows) x (2 cc-chunks). Tile 32x2 out px.
// Swizzle: slot ^= (rec>>1)&3 so (rec&1,slot) covers all 8 16B positions.
__global__ __launch_bounds__(256, 4) void conv1_fused(
    const unsigned short* __restrict__ h0, const unsigned short* __restrict__ wfr,
    const unsigned short* __restrict__ wc0fr, const float* __restrict__ bias,
    const float* __restrict__ bc0, unsigned short* __restrict__ ycl)
{
    __shared__ unsigned short lds[10400];        // max(325*32, 64*128) ush
    const int tid = threadIdx.x;
    const int wv = tid >> 6, lane = tid & 63;
    const int p = lane & 31, h = lane >> 5;
    const int r = wv >> 1, cc = wv & 1;          // wave = (row, cc-chunk)
    const int bx = blockIdx.x % 5, by = blockIdx.x / 5;
    const int ox0 = bx * 32, oy0 = by * 2;
    const int n = blockIdx.z;

    f32x16 acc;
    #pragma unroll
    for (int q = 0; q < 4; ++q) {
        f32x4 b4 = *reinterpret_cast<const f32x4*>(&bias[cc * 32 + q * 8 + 4 * h]);
        #pragma unroll
        for (int r2 = 0; r2 < 4; ++r2) acc[q * 4 + r2] = b4[r2];
    }

    // K-loop: 2 rounds (ci halves), parity tiles:
    //   ee[0,64)W32(2r), eo[64,130)W33(2r), oe[130,226)W32(3r), oo[226,325)W33(3r)
    for (int c = 0; c < 2; ++c) {
        __syncthreads();
        for (int u = tid; u < 1300; u += 256) {
            const int rec = u >> 2, s = u & 3;
            int gp, row, col;
            if (rec < 64)       { gp = 0; row = rec >> 5;  col = rec & 31; }
            else if (rec < 130) { gp = 1; int r2 = rec - 64;  row = r2 / 33; col = r2 - row * 33; }
            else if (rec < 226) { gp = 2; int r2 = rec - 130; row = r2 >> 5; col = r2 & 31; }
            else                { gp = 3; int r2 = rec - 226; row = r2 / 33; col = r2 - row * 33; }
            const int gr = (gp >= 2) ? oy0 - 1 + row : oy0 + row;
            const int gc = (gp & 1)  ? ox0 - 1 + col : ox0 + col;
            uint4v val = {0, 0, 0, 0};
            if (gr >= 0 && gr < 160 && gc >= 0 && gc < 160)
                val = *reinterpret_cast<const uint4v*>(
                    h0 + (((long)n * 4 + gp) * 25600 + gr * 160 + gc) * 64 + (4 * c + s) * 8);
            *reinterpret_cast<uint4v*>(&lds[rec * 32 + ((s ^ ((rec >> 1) & 3)) * 8)]) = val;
        }
        __syncthreads();

        #pragma unroll
        for (int tap = 0; tap < 9; ++tap) {
            const int dy = tap / 3 - 1, dx = tap % 3 - 1;
            const int ppy = dy & 1, ppx = dx & 1;
            const int toy = ppy ? ((dy == -1) ? 0 : 1) : 0;
            const int tox = ppx ? ((dx == -1) ? 0 : 1) : 0;
            const int gp = ppy * 2 + ppx;
            const int base = (gp == 0) ? 0 : (gp == 1) ? 64 : (gp == 2) ? 130 : 226;
            const int W = ppx ? 33 : 32;
            const int rec = base + (ppy ? (r + toy) : r) * W + (p + tox);
            const unsigned short* t = &lds[rec * 32];
            const int pm = (rec >> 1) & 3;
            short8 Bh = *reinterpret_cast<const short8*>(t + (((2 * h)     ^ pm) * 8));
            short8 Bl = *reinterpret_cast<const short8*>(t + (((2 * h + 1) ^ pm) * 8));
            const unsigned short* fb = wfr + ((tap * 2 + c) * 2 + cc) * 1024 + lane * 8;
            short8 Awh = *reinterpret_cast<const short8*>(fb);
            short8 Awl = *reinterpret_cast<const short8*>(fb + 512);
            acc = __builtin_amdgcn_mfma_f32_32x32x16_bf16(Awh, Bh, acc, 0, 0, 0);
            acc = __builtin_amdgcn_mfma_f32_32x32x16_bf16(Awh, Bl, acc, 0, 0, 0);
            acc = __builtin_amdgcn_mfma_f32_32x32x16_bf16(Awl, Bh, acc, 0, 0, 0);
        }
    }

    // ---- stage y = silu(conv1) to LDS: 64 recs x 128 ush, slot-XOR swizzle
    __syncthreads();
    {
        const int rec2 = r * 32 + p;
        #pragma unroll
        for (int q = 0; q < 4; ++q) {
            ushort4v hv, lv;
            #pragma unroll
            for (int r2 = 0; r2 < 4; ++r2) {
                float v = silu_f(acc[q * 4 + r2]);
                unsigned short hh = bfhi(v);
                hv[r2] = hh; lv[r2] = bfhi(v - bf2f(hh));
            }
            const int lsh = (2 * (cc * 4 + q))     ^ (rec2 & 15);
            const int lsl = (2 * (cc * 4 + q) + 1) ^ (rec2 & 15);
            *reinterpret_cast<ushort4v*>(&lds[rec2 * 128 + lsh * 8 + 4 * h]) = hv;
            *reinterpret_cast<ushort4v*>(&lds[rec2 * 128 + lsl * 8 + 4 * h]) = lv;
        }
    }
    __syncthreads();

    // ---- wc0: 1x1 64->64 from LDS y-tile; wave owns cc output chunk
    f32x16 a2;
    #pragma unroll
    for (int q = 0; q < 4; ++q) {
        f32x4 b4 = *reinterpret_cast<const f32x4*>(&bc0[cc * 32 + q * 8 + 4 * h]);
        #pragma unroll
        for (int r2 = 0; r2 < 4; ++r2) a2[q * 4 + r2] = b4[r2];
    }
    {
        const int rec2 = r * 32 + p;
        #pragma unroll
        for (int rnd = 0; rnd < 4; ++rnd) {
            const int sh = (4 * rnd + 2 * h)     ^ (rec2 & 15);
            const int sl = (4 * rnd + 2 * h + 1) ^ (rec2 & 15);
            short8 Bh = *reinterpret_cast<const short8*>(&lds[rec2 * 128 + sh * 8]);
            short8 Bl = *reinterpret_cast<const short8*>(&lds[rec2 * 128 + sl * 8]);
            const unsigned short* fb = wc0fr + (rnd * 2 + cc) * 1024 + lane * 8;
            short8 Awh = *reinterpret_cast<const short8*>(fb);
            short8 Awl = *reinterpret_cast<const short8*>(fb + 512);
            a2 = __builtin_amdgcn_mfma_f32_32x32x16_bf16(Awh, Bh, a2, 0, 0, 0);
            a2 = __builtin_amdgcn_mfma_f32_32x32x16_bf16(Awh, Bl, a2, 0, 0, 0);
            a2 = __builtin_amdgcn_mfma_f32_32x32x16_bf16(Awl, Bh, a2, 0, 0, 0);
        }
    }

    const int oy = oy0 + r;
    unsigned short* op = ycl + ((long)n * 25600 + (long)oy * 160 + ox0 + p) * 128;
    #pragma unroll
    for (int q = 0; q < 4; ++q) {
        ushort4v hv, lv;
        #pragma unroll
        for (int r2 = 0; r2 < 4; ++r2) {
            float v = silu_f(a2[q * 4 + r2]);
            unsigned short hh = bfhi(v);
            hv[r2] = hh; lv[r2] = bfhi(v - bf2f(hh));
        }
        const int gq = cc * 4 + q;
        *reinterpret_cast<ushort4v*>(op + gq * 16 + 4 * h)     = hv;
        *reinterpret_cast<ushort4v*>(op + gq * 16 + 8 + 4 * h) = lv;
    }
}

// ============ wb: 32->32 s1 3x3, tile-only LDS, frags from global ===========
template <bool RESID>
__global__ __launch_bounds__(512, 4) void wb3x3(
    const unsigned short* __restrict__ in, int inRec, int inSlot0,
    const unsigned short* __restrict__ wfr, const float* __restrict__ bias,
    unsigned short* __restrict__ outb, const unsigned short* __restrict__ resid)
{
    __shared__ unsigned short lds[21760];        // tile 34x10 x 64 ush (43.5 KB)
    const int tid = threadIdx.x;
    const int wv = tid >> 6, lane = tid & 63;
    const int p = lane & 31, h = lane >> 5;
    const int bx = blockIdx.x % 5, by = blockIdx.x / 5;
    const int ox0 = bx * 32, oy0 = by * 8;
    const int n = blockIdx.z;

    for (int u = tid; u < 2720; u += 512) {      // tile 34x10, 8 slots/rec
        const int rec = u >> 3, s = u & 7;
        const int row = rec / 34, col = rec - row * 34;
        const int gr = oy0 - 1 + row, gc = ox0 - 1 + col;
        uint4v val = {0, 0, 0, 0};
        if (gr >= 0 && gr < 160 && gc >= 0 && gc < 160)
            val = *reinterpret_cast<const uint4v*>(
                in + ((long)n * 25600 + gr * 160 + gc) * inRec + (inSlot0 + s) * 8);
        *reinterpret_cast<uint4v*>(&lds[rec * 64 + ((s ^ (rec & 7)) * 8)]) = val;
    }

    f32x16 acc;
    #pragma unroll
    for (int q = 0; q < 4; ++q) {
        f32x4 b4 = *reinterpret_cast<const f32x4*>(&bias[q * 8 + 4 * h]);
        #pragma unroll
        for (int r = 0; r < 4; ++r) acc[q * 4 + r] = b4[r];
    }
    __syncthreads();

    #pragma unroll
    for (int tap = 0; tap < 9; ++tap) {
        const int dy = tap / 3 - 1, dx = tap % 3 - 1;
        const int rec = (wv + dy + 1) * 34 + (p + dx + 1);
        const unsigned short* t = &lds[rec * 64];
        short8 Bh[2], Bl[2];
        #pragma unroll
        for (int rnd = 0; rnd < 2; ++rnd) {
            Bh[rnd] = *reinterpret_cast<const short8*>(t + (((rnd*4 + 2*h)     ^ (rec & 7)) * 8));
            Bl[rnd] = *reinterpret_cast<const short8*>(t + (((rnd*4 + 2*h + 1) ^ (rec & 7)) * 8));
        }
        #pragma unroll
        for (int rnd = 0; rnd < 2; ++rnd) {
            const unsigned short* fb = wfr + (tap * 2 + rnd) * 1024 + lane * 8;
            short8 Awh = *reinterpret_cast<const short8*>(fb);
            short8 Awl = *reinterpret_cast<const short8*>(fb + 512);
            acc = __builtin_amdgcn_mfma_f32_32x32x16_bf16(Awh, Bh[rnd], acc, 0, 0, 0);
            acc = __builtin_amdgcn_mfma_f32_32x32x16_bf16(Awh, Bl[rnd], acc, 0, 0, 0);
            acc = __builtin_amdgcn_mfma_f32_32x32x16_bf16(Awl, Bh[rnd], acc, 0, 0, 0);
        }
    }

    const int oy = oy0 + wv;
    const long prow = (long)n * 25600 + (long)oy * 160 + ox0 + p;
    unsigned short* op = outb + prow * 64;
    const unsigned short* rp = RESID ? resid + prow * 128 : nullptr;
    #pragma unroll
    for (int q = 0; q < 4; ++q) {
        ushort4v hv, lv;
        float vs[4];
        #pragma unroll
        for (int r = 0; r < 4; ++r) vs[r] = silu_f(acc[q * 4 + r]);
        if (RESID) {
            ushort4v rh = *reinterpret_cast<const ushort4v*>(rp + (q + 4) * 16 + 4 * h);
            ushort4v rl = *reinterpret_cast<const ushort4v*>(rp + (q + 4) * 16 + 8 + 4 * h);
            #pragma unroll
            for (int r = 0; r < 4; ++r) vs[r] += bf2f(rh[r]) + bf2f(rl[r]);
        }
        #pragma unroll
        for (int r = 0; r < 4; ++r) {
            unsigned short hh = bfhi(vs[r]);
            hv[r] = hh; lv[r] = bfhi(vs[r] - bf2f(hh));
        }
        *reinterpret_cast<ushort4v*>(op + q * 16 + 4 * h)     = hv;
        *reinterpret_cast<ushort4v*>(op + q * 16 + 8 + 4 * h) = lv;
    }
}

// ============ wc1: 1x1 concat(96->64), zero LDS, frags from global ==========
template <int R1, int R2, bool POUT>
__global__ __launch_bounds__(512, 4) void wc1x1(
    const unsigned short* __restrict__ in1, int rec1,
    const unsigned short* __restrict__ in2, int rec2,
    const unsigned short* __restrict__ wfr, const float* __restrict__ bias,
    unsigned short* __restrict__ outb)
{
    constexpr int RT = R1 + R2;
    const int tid = threadIdx.x;
    const int wv = tid >> 6, lane = tid & 63;
    const int p = lane & 31, h = lane >> 5;
    const int n = blockIdx.z;
    const int px0 = blockIdx.x * 512;

    f32x16 acc[2][2];
    #pragma unroll
    for (int cc = 0; cc < 2; ++cc)
        #pragma unroll
        for (int q = 0; q < 4; ++q) {
            f32x4 b4 = *reinterpret_cast<const f32x4*>(&bias[cc * 32 + q * 8 + 4 * h]);
            #pragma unroll
            for (int r = 0; r < 4; ++r) { acc[cc][0][q*4+r] = b4[r]; acc[cc][1][q*4+r] = b4[r]; }
        }

    #pragma unroll
    for (int rnd = 0; rnd < RT; ++rnd) {
        const unsigned short* bp = (rnd < R1) ? in1 : in2;
        const int recN = (rnd < R1) ? rec1 : rec2;
        const int s0 = 4 * ((rnd < R1) ? rnd : rnd - R1);
        #pragma unroll
        for (int k = 0; k < 2; ++k) {
            const int px = px0 + (wv * 2 + k) * 32 + p;
            const unsigned short* sp = bp + ((long)n * 25600 + px) * recN + (s0 + 2 * h) * 8;
            short8 Bh = *reinterpret_cast<const short8*>(sp);
            short8 Bl = *reinterpret_cast<const short8*>(sp + 8);
            #pragma unroll
            for (int cc = 0; cc < 2; ++cc) {
                const unsigned short* fb = wfr + (rnd * 2 + cc) * 1024 + lane * 8;
                short8 Awh = *reinterpret_cast<const short8*>(fb);
                short8 Awl = *reinterpret_cast<const short8*>(fb + 512);
                acc[cc][k] = __builtin_amdgcn_mfma_f32_32x32x16_bf16(Awh, Bh, acc[cc][k], 0, 0, 0);
                acc[cc][k] = __builtin_amdgcn_mfma_f32_32x32x16_bf16(Awh, Bl, acc[cc][k], 0, 0, 0);
                acc[cc][k] = __builtin_amdgcn_mfma_f32_32x32x16_bf16(Awl, Bh, acc[cc][k], 0, 0, 0);
            }
        }
    }

    #pragma unroll
    for (int k = 0; k < 2; ++k) {
        const int px = px0 + (wv * 2 + k) * 32 + p;
        unsigned short* op;
        if (POUT) {
            const int y = px / 160, xx = px % 160;
            const int pl = (y & 1) * 2 + (xx & 1);
            op = outb + (((long)n * 4 + pl) * 6400 + (y >> 1) * 80 + (xx >> 1)) * 128;
        } else {
            op = outb + ((long)n * 25600 + px) * 128;
        }
        #pragma unroll
        for (int cc = 0; cc < 2; ++cc)
            #pragma unroll
            for (int q = 0; q < 4; ++q) {
                ushort4v hv, lv;
                #pragma unroll
                for (int r = 0; r < 4; ++r) {
                    float v = silu_f(acc[cc][k][q * 4 + r]);
                    unsigned short hh = bfhi(v);
                    hv[r] = hh; lv[r] = bfhi(v - bf2f(hh));
                }
                const int gq = cc * 4 + q;
                *reinterpret_cast<ushort4v*>(op + gq * 16 + 4 * h)     = hv;
                *reinterpret_cast<ushort4v*>(op + gq * 16 + 8 + 4 * h) = lv;
            }
    }
}

// ============ conv3: 64->128 s2 3x3, SINGLE kernel, 4 staging rounds ========
__global__ __launch_bounds__(512, 4) void conv3_one(
    const unsigned short* __restrict__ h2p, const unsigned short* __restrict__ wfr,
    const float* __restrict__ bias, float* __restrict__ outf)
{
    __shared__ unsigned short lds[34848];        // tile 1089 x 32 ush (69.7 KB)
    const int tid = threadIdx.x;
    const int wv = tid >> 6, lane = tid & 63;
    const int p = lane & 31, h = lane >> 5;
    const int bx = blockIdx.x % 5, by = blockIdx.x / 5;
    const int ox0 = bx * 16, oy0 = by * 16;
    const int cg = blockIdx.y;
    const int co0 = cg * 64;
    const int n = blockIdx.z;

    f32x16 acc[2];
    #pragma unroll
    for (int cc = 0; cc < 2; ++cc)
        #pragma unroll
        for (int q = 0; q < 4; ++q) {
            f32x4 b4 = *reinterpret_cast<const f32x4*>(&bias[co0 + cc * 32 + q * 8 + 4 * h]);
            #pragma unroll
            for (int r = 0; r < 4; ++r) acc[cc][q * 4 + r] = b4[r];
        }

    for (int rr = 0; rr < 4; ++rr) {
        __syncthreads();
        for (int u = tid; u < 4356; u += 512) {
            const int rec = u >> 2, s = u & 3;
            int gp, row, col;
            if (rec < 256)      { gp = 0; row = rec >> 4; col = rec & 15; }
            else if (rec < 528) { gp = 1; int r2 = rec - 256; row = r2 / 17; col = r2 - row * 17; }
            else if (rec < 800) { gp = 2; int r2 = rec - 528; row = r2 >> 4; col = r2 & 15; }
            else                { gp = 3; int r2 = rec - 800; row = r2 / 17; col = r2 - row * 17; }
            const int gr = (gp >= 2) ? oy0 - 1 + row : oy0 + row;
            const int gc = (gp & 1)  ? ox0 - 1 + col : ox0 + col;
            uint4v val = {0, 0, 0, 0};
            if (gr >= 0 && gr < 80 && gc >= 0 && gc < 80)
                val = *reinterpret_cast<const uint4v*>(
                    h2p + (((long)n * 4 + gp) * 6400 + gr * 80 + gc) * 128 + (rr * 4 + s) * 8);
            *reinterpret_cast<uint4v*>(&lds[rec * 32 + ((s ^ ((rec >> 1) & 3)) * 8)]) = val;
        }
        __syncthreads();

        #pragma unroll
        for (int tap = 0; tap < 9; ++tap) {
            const int dy = tap / 3 - 1, dx = tap % 3 - 1;
            const int ppy = dy & 1, ppx = dx & 1;
            const int toy = ppy ? ((dy == -1) ? 0 : 1) : 0;
            const int tox = ppx ? ((dx == -1) ? 0 : 1) : 0;
            const int gp = ppy * 2 + ppx;
            const int base = (gp == 0) ? 0 : (gp == 1) ? 256 : (gp == 2) ? 528 : 800;
            const int W = ppx ? 17 : 16;
            const int rl = wv * 2 + (p >> 4), cl = p & 15;
            const int rec = base + (ppy ? (rl + toy) : rl) * W + (cl + tox);
            const unsigned short* t = &lds[rec * 32];
            const int pm = (rec >> 1) & 3;
            short8 Bh = *reinterpret_cast<const short8*>(t + (((2*h)     ^ pm) * 8));
            short8 Bl = *reinterpret_cast<const short8*>(t + (((2*h + 1) ^ pm) * 8));
            #pragma unroll
            for (int cc = 0; cc < 2; ++cc) {
                const unsigned short* fb =
                    wfr + (((cg * 9 + tap) * 4 + rr) * 2 + cc) * 1024 + lane * 8;
                short8 Awh = *reinterpret_cast<const short8*>(fb);
                short8 Awl = *reinterpret_cast<const short8*>(fb + 512);
                acc[cc] = __builtin_amdgcn_mfma_f32_32x32x16_bf16(Awh, Bh, acc[cc], 0, 0, 0);
                acc[cc] = __builtin_amdgcn_mfma_f32_32x32x16_bf16(Awh, Bl, acc[cc], 0, 0, 0);
                acc[cc] = __builtin_amdgcn_mfma_f32_32x32x16_bf16(Awl, Bh, acc[cc], 0, 0, 0);
            }
        }
    }

    const int rl = wv * 2 + (p >> 4);
    const int oy = oy0 + rl;
    const int pxg = oy * 80 + ox0 + (p & 15);
    #pragma unroll
    for (int cc = 0; cc < 2; ++cc)
        #pragma unroll
        for (int q = 0; q < 4; ++q)
            #pragma unroll
            for (int r = 0; r < 4; ++r) {
                const int co = co0 + cc * 32 + q * 8 + 4 * h + r;
                outf[((long)n * 128 + co) * 6400 + pxg] = silu_f(acc[cc][q * 4 + r]);
            }
}

extern "C" void kernel_launch(void* const* d_in, const int* in_sizes, int n_in,
                              void* d_out, int out_size, void* d_ws, size_t ws_size,
                              hipStream_t stream) {
    const float* x   = (const float*)d_in[0];
    const float* w0  = (const float*)d_in[1];
    const float* b0  = (const float*)d_in[2];
    const float* w1  = (const float*)d_in[3];
    const float* b1  = (const float*)d_in[4];
    const float* wc0 = (const float*)d_in[5];
    const float* bc0 = (const float*)d_in[6];
    const float* wb1 = (const float*)d_in[7];
    const float* bb1 = (const float*)d_in[8];
    const float* wb2 = (const float*)d_in[9];
    const float* bb2 = (const float*)d_in[10];
    const float* wc1 = (const float*)d_in[11];
    const float* bc1 = (const float*)d_in[12];
    const float* w3  = (const float*)d_in[13];
    const float* b3  = (const float*)d_in[14];

    unsigned short* u = (unsigned short*)d_ws;
    // ws (ushort offsets), peak 157,286,400 B:
    //   h0p [n][4][25600][64] @0..52.4M (dead after conv1_fused)
    //   ycl [n][25600][128]   @52,428,800
    //   b1cl @26,214,400 ; bcl @39,321,600 ; h2p @0 ; w3a @26,214,400
    unsigned short* h0p  = u;
    unsigned short* ycl  = u + 52428800L;
    unsigned short* b1cl = u + 26214400L;
    unsigned short* bcl  = u + 39321600L;
    unsigned short* h2p  = u;
    unsigned short* w3a  = u + 26214400L;

    // small-conv frag arena lives in d_out (conv3 overwrites all of d_out)
    unsigned short* wsa = (unsigned short*)d_out;
    unsigned short* a_conv1 = wsa;
    unsigned short* a_wc0   = wsa + 36 * 1024;
    unsigned short* a_wb1   = wsa + 44 * 1024;
    unsigned short* a_wb2   = wsa + 62 * 1024;
    unsigned short* a_wc1   = wsa + 80 * 1024;

    prep_small<<<dim3(24, 1, 1), dim3(256, 1, 1), 0, stream>>>(
        w1, wc0, wb1, wb2, wc1, w0, wsa);

    conv0_mfma<<<dim3(100, 4, 8), dim3(512, 1, 1), 0, stream>>>(x, wsa, b0, h0p);

    // conv1+wc0 fused: 400 tiles (5 bx x 80 by) x 8 n, 256-thread blocks
    conv1_fused<<<dim3(400, 1, 8), dim3(256, 1, 1), 0, stream>>>(
        h0p, a_conv1, a_wc0, b1, bc0, ycl);

    wb3x3<false><<<dim3(100, 1, 8), dim3(512, 1, 1), 0, stream>>>(
        ycl, 128, 8, a_wb1, bb1, b1cl, nullptr);

    wb3x3<true><<<dim3(100, 1, 8), dim3(512, 1, 1), 0, stream>>>(
        b1cl, 64, 0, a_wb2, bb2, bcl, ycl);

    prep_w3<<<dim3(36, 1, 1), dim3(256, 1, 1), 0, stream>>>(w3, w3a);

    wc1x1<4, 2, true><<<dim3(50, 1, 8), dim3(512, 1, 1), 0, stream>>>(
        ycl, 128, bcl, 64, a_wc1, bc1, h2p);

    conv3_one<<<dim3(25, 2, 8), dim3(512, 1, 1), 0, stream>>>(h2p, w3a, b3, (float*)d_out);
}

// Round 12
// 246.235 us; speedup vs baseline: 2.2328x; 1.1185x over previous
//
#include <hip/hip_runtime.h>
#include <hip/hip_bf16.h>

typedef __attribute__((ext_vector_type(8))) short short8;
typedef __attribute__((ext_vector_type(16))) float f32x16;
typedef __attribute__((ext_vector_type(4))) float f32x4;
typedef __attribute__((ext_vector_type(4))) unsigned int uint4v;
typedef __attribute__((ext_vector_type(4))) unsigned short ushort4v;

__device__ __forceinline__ float silu_f(float v) {
    return v * __builtin_amdgcn_rcpf(1.0f + __expf(-v));
}
__device__ __forceinline__ unsigned short bfhi(float v) {
    __hip_bfloat16 h = __float2bfloat16(v);
    return *reinterpret_cast<unsigned short*>(&h);
}
__device__ __forceinline__ float bf2f(unsigned short u) {
    __hip_bfloat16 h;
    *reinterpret_cast<unsigned short*>(&h) = u;
    return __bfloat162float(h);
}

// ======= weight prep: f32 -> bf16 hi/lo fragments (pf*1024 + lane*8, lo +512)
// arena (in d_out): conv1 @0 (36pf), wc0 @36 (8pf), wb1 @44 (18pf),
//   wb2 @62 (18pf), wc1 @80 (12pf), w0 @92 (2pf; K=32 padded from 27). 94 pf.
__global__ __launch_bounds__(256) void prep_small(
    const float* __restrict__ w1, const float* __restrict__ wc0,
    const float* __restrict__ wb1, const float* __restrict__ wb2,
    const float* __restrict__ wc1, const float* __restrict__ w0,
    unsigned short* __restrict__ arena)
{
    const int u = blockIdx.x * 256 + threadIdx.x;   // 0..6015
    if (u >= 6016) return;
    const int lane = u & 63, pf = u >> 6;
    float wv[8];
    if (pf < 36) {
        const int q = pf, cc = q & 1, rnd = (q >> 1) & 1, tap = q >> 2;
        const int co = cc * 32 + (lane & 31), ci0 = rnd * 16 + (lane >> 5) * 8;
        #pragma unroll
        for (int j = 0; j < 8; ++j) wv[j] = w1[(co * 32 + ci0 + j) * 9 + tap];
    } else if (pf < 44) {
        const int q = pf - 36, cc = q & 1, rnd = q >> 1;
        const int co = cc * 32 + (lane & 31), ci0 = rnd * 16 + (lane >> 5) * 8;
        #pragma unroll
        for (int j = 0; j < 8; ++j) wv[j] = wc0[co * 64 + ci0 + j];
    } else if (pf < 62) {
        const int q = pf - 44, rnd = q & 1, tap = q >> 1;
        const int co = lane & 31, ci0 = rnd * 16 + (lane >> 5) * 8;
        #pragma unroll
        for (int j = 0; j < 8; ++j) wv[j] = wb1[(co * 32 + ci0 + j) * 9 + tap];
    } else if (pf < 80) {
        const int q = pf - 62, rnd = q & 1, tap = q >> 1;
        const int co = lane & 31, ci0 = rnd * 16 + (lane >> 5) * 8;
        #pragma unroll
        for (int j = 0; j < 8; ++j) wv[j] = wb2[(co * 32 + ci0 + j) * 9 + tap];
    } else if (pf < 92) {
        const int q = pf - 80, cc = q & 1, rnd = q >> 1;
        const int co = cc * 32 + (lane & 31), ci0 = rnd * 16 + (lane >> 5) * 8;
        #pragma unroll
        for (int j = 0; j < 8; ++j) wv[j] = wc1[co * 96 + ci0 + j];
    } else {
        const int co = lane & 31;
        const int k0 = (pf - 92) * 16 + (lane >> 5) * 8;
        #pragma unroll
        for (int j = 0; j < 8; ++j) {
            const int k = k0 + j;
            wv[j] = (k < 27) ? w0[(co * 3 + k / 9) * 9 + (k % 9)] : 0.0f;
        }
    }
    unsigned short hs[8], ls[8];
    #pragma unroll
    for (int j = 0; j < 8; ++j) {
        unsigned short hh = bfhi(wv[j]);
        hs[j] = hh; ls[j] = bfhi(wv[j] - bf2f(hh));
    }
    *reinterpret_cast<short8*>(&arena[pf * 1024 + lane * 8])       = *(short8*)hs;
    *reinterpret_cast<short8*>(&arena[pf * 1024 + 512 + lane * 8]) = *(short8*)ls;
}

// arena2 (in ws): w3, pf = ((cg*9+tap)*4 + rr)*2+cc, rr = ci/16. 144 pf
__global__ __launch_bounds__(256) void prep_w3(
    const float* __restrict__ w3, unsigned short* __restrict__ arena)
{
    const int u = blockIdx.x * 256 + threadIdx.x;   // 0..9215
    const int lane = u & 63, pf = u >> 6;
    const int cc = pf & 1, rr = (pf >> 1) & 3, t9 = pf >> 3;
    const int tap = t9 % 9, cg = t9 / 9;
    const int co = cg * 64 + cc * 32 + (lane & 31);
    const int ci0 = rr * 16 + (lane >> 5) * 8;
    unsigned short hs[8], ls[8];
    #pragma unroll
    for (int j = 0; j < 8; ++j) {
        float wv = w3[(co * 64 + ci0 + j) * 9 + tap];
        unsigned short hh = bfhi(wv);
        hs[j] = hh; ls[j] = bfhi(wv - bf2f(hh));
    }
    *reinterpret_cast<short8*>(&arena[pf * 1024 + lane * 8])       = *(short8*)hs;
    *reinterpret_cast<short8*>(&arena[pf * 1024 + 512 + lane * 8]) = *(short8*)ls;
}

// ============ STEM: conv0 (3->32 s2) + conv1 (32->64 s2 3x3) + wc0 (1x1) ====
// One kernel, 256 threads = 4 waves = (2 rows r) x (2 cc). Out tile 32x2 -> ycl.
// Phase A: compute 325 h0 parity-recs from x via K=32 gather-GEMM into LDS
//   (rec layout: 64 ush = 8 slots of 16B; slot 2g = granule-g hi, 2g+1 = lo,
//    swizzled slot^(rec&7)). Zero barriers in K-loop; no h0 global traffic.
__global__ __launch_bounds__(256, 4) void stem_fused(
    const float* __restrict__ x, const unsigned short* __restrict__ wfr,
    const unsigned short* __restrict__ wc0fr, const float* __restrict__ b0,
    const float* __restrict__ bias, const float* __restrict__ bc0,
    unsigned short* __restrict__ ycl)
{
    __shared__ unsigned short lds[20800];        // 325 recs x 64 ush = 41.6 KB
    const int tid = threadIdx.x;
    const int wv = tid >> 6, lane = tid & 63;
    const int p = lane & 31, h = lane >> 5;
    const int r = wv >> 1, cc = wv & 1;
    const int bx = blockIdx.x % 5, by = blockIdx.x / 5;
    const int ox0 = bx * 32, oy0 = by * 2;
    const int n = blockIdx.z;
    const float* xb = x + (long)n * 1228800;

    // per-thread tap descriptors: doff[idx] for k = (idx>>3)*16 + h*8 + (idx&7)
    const int h8 = h * 8;
    int doff[16];
    #pragma unroll
    for (int idx = 0; idx < 16; ++idx) {
        const int k = (idx >> 3) * 16 + h8 + (idx & 7);
        if (k < 27) {
            const int ci = (k * 57) >> 9;
            const int tap = k - 9 * ci;
            const int dy = (tap * 11) >> 5, dx = tap - 3 * dy;
            doff[idx] = ci * 409600 + (dy - 1) * 640 + (dx - 1);
        } else {
            doff[idx] = 0;
        }
    }

    // ---- phase A: 11 groups of 32 recs; group g -> wave (g&3), iter (g>>2)
    for (int it = 0; it < 3; ++it) {
        const int g = it * 4 + wv;
        if (g < 11) {
            const int rc = g * 32 + p;
            const bool validR = rc < 325;
            const int rec_c = validR ? rc : 324;
            int gp, row, col;
            if (rec_c < 64)       { gp = 0; row = rec_c >> 5; col = rec_c & 31; }
            else if (rec_c < 130) { gp = 1; int r2 = rec_c - 64;  row = r2 / 33; col = r2 - row * 33; }
            else if (rec_c < 226) { gp = 2; int r2 = rec_c - 130; row = r2 >> 5; col = r2 & 31; }
            else                  { gp = 3; int r2 = rec_c - 226; row = r2 / 33; col = r2 - row * 33; }
            const int gr = (gp >= 2) ? oy0 - 1 + row : oy0 + row;
            const int gc = (gp & 1)  ? ox0 - 1 + col : ox0 + col;
            const bool valid = validR && ((unsigned)gr < 160u) && ((unsigned)gc < 160u);
            const int Y = 2 * gr + (gp >> 1);
            const int X = 2 * gc + (gp & 1);
            const int Bsafe = valid ? (1280 * Y + 2 * X) : 641;
            const bool interior = valid && gr > 0 && gr < 159 && gc > 0 && gc < 159;
            const bool fastw = __all(interior);

            f32x16 a0;
            #pragma unroll
            for (int q = 0; q < 4; ++q) {
                f32x4 b4 = *reinterpret_cast<const f32x4*>(&b0[q * 8 + 4 * h]);
                #pragma unroll
                for (int r2 = 0; r2 < 4; ++r2) a0[q * 4 + r2] = b4[r2];
            }

            #pragma unroll
            for (int rnd = 0; rnd < 2; ++rnd) {
                unsigned short hs[8], ls[8];
                if (fastw) {
                    #pragma unroll
                    for (int j = 0; j < 8; ++j) {
                        float v = xb[Bsafe + doff[rnd * 8 + j]];
                        if (rnd == 1 && j >= 3) v = (h == 0) ? v : 0.0f;
                        unsigned short hh = bfhi(v);
                        hs[j] = hh; ls[j] = bfhi(v - bf2f(hh));
                    }
                } else {
                    #pragma unroll
                    for (int j = 0; j < 8; ++j) {
                        const int k = rnd * 16 + h8 + j;
                        const int ci = (k * 57) >> 9;
                        const int tap = k - 9 * ci;
                        const int dy = (tap * 11) >> 5, dx = tap - 3 * dy;
                        const int iy = 2 * Y + dy - 1;
                        const int ix = 2 * X + dx - 1;
                        bool ok = valid && ((unsigned)iy < 640u) && ((unsigned)ix < 640u);
                        if (rnd == 1 && j >= 3) ok = ok && (h == 0);
                        float v = ok ? xb[Bsafe + doff[rnd * 8 + j]] : 0.0f;
                        unsigned short hh = bfhi(v);
                        hs[j] = hh; ls[j] = bfhi(v - bf2f(hh));
                    }
                }
                short8 Bh = *(short8*)hs, Bl = *(short8*)ls;
                const unsigned short* fb = wfr + (92 + rnd) * 1024 + lane * 8;
                short8 Awh = *reinterpret_cast<const short8*>(fb);
                short8 Awl = *reinterpret_cast<const short8*>(fb + 512);
                a0 = __builtin_amdgcn_mfma_f32_32x32x16_bf16(Awh, Bh, a0, 0, 0, 0);
                a0 = __builtin_amdgcn_mfma_f32_32x32x16_bf16(Awh, Bl, a0, 0, 0, 0);
                a0 = __builtin_amdgcn_mfma_f32_32x32x16_bf16(Awl, Bh, a0, 0, 0, 0);
            }

            if (validR) {
                const int pm = rc & 7;
                #pragma unroll
                for (int q = 0; q < 4; ++q) {
                    ushort4v hv, lv;
                    #pragma unroll
                    for (int r2 = 0; r2 < 4; ++r2) {
                        float v = valid ? silu_f(a0[q * 4 + r2]) : 0.0f;
                        unsigned short hh = bfhi(v);
                        hv[r2] = hh; lv[r2] = bfhi(v - bf2f(hh));
                    }
                    *reinterpret_cast<ushort4v*>(&lds[rc * 64 + (((2 * q)     ^ pm) * 8) + 4 * h]) = hv;
                    *reinterpret_cast<ushort4v*>(&lds[rc * 64 + (((2 * q + 1) ^ pm) * 8) + 4 * h]) = lv;
                }
            }
        }
    }
    __syncthreads();

    // ---- conv1 K-loop from LDS h0 tile (no staging, no barriers)
    f32x16 acc;
    #pragma unroll
    for (int q = 0; q < 4; ++q) {
        f32x4 b4 = *reinterpret_cast<const f32x4*>(&bias[cc * 32 + q * 8 + 4 * h]);
        #pragma unroll
        for (int r2 = 0; r2 < 4; ++r2) acc[q * 4 + r2] = b4[r2];
    }
    #pragma unroll
    for (int c = 0; c < 2; ++c) {
        #pragma unroll
        for (int tap = 0; tap < 9; ++tap) {
            const int dy = tap / 3 - 1, dx = tap % 3 - 1;
            const int ppy = dy & 1, ppx = dx & 1;
            const int toy = ppy ? ((dy == -1) ? 0 : 1) : 0;
            const int tox = ppx ? ((dx == -1) ? 0 : 1) : 0;
            const int gp = ppy * 2 + ppx;
            const int base = (gp == 0) ? 0 : (gp == 1) ? 64 : (gp == 2) ? 130 : 226;
            const int W = ppx ? 33 : 32;
            const int rec = base + (ppy ? (r + toy) : r) * W + (p + tox);
            const unsigned short* t = &lds[rec * 64];
            const int pm = rec & 7;
            short8 Bh = *reinterpret_cast<const short8*>(t + (((4 * c + 2 * h)     ^ pm) * 8));
            short8 Bl = *reinterpret_cast<const short8*>(t + (((4 * c + 2 * h + 1) ^ pm) * 8));
            const unsigned short* fb = wfr + ((tap * 2 + c) * 2 + cc) * 1024 + lane * 8;
            short8 Awh = *reinterpret_cast<const short8*>(fb);
            short8 Awl = *reinterpret_cast<const short8*>(fb + 512);
            acc = __builtin_amdgcn_mfma_f32_32x32x16_bf16(Awh, Bh, acc, 0, 0, 0);
            acc = __builtin_amdgcn_mfma_f32_32x32x16_bf16(Awh, Bl, acc, 0, 0, 0);
            acc = __builtin_amdgcn_mfma_f32_32x32x16_bf16(Awl, Bh, acc, 0, 0, 0);
        }
    }

    // ---- stage y = silu(conv1) to LDS (64 recs x 128 ush), aliases h0 tile
    __syncthreads();
    {
        const int rec2 = r * 32 + p;
        #pragma unroll
        for (int q = 0; q < 4; ++q) {
            ushort4v hv, lv;
            #pragma unroll
            for (int r2 = 0; r2 < 4; ++r2) {
                float v = silu_f(acc[q * 4 + r2]);
                unsigned short hh = bfhi(v);
                hv[r2] = hh; lv[r2] = bfhi(v - bf2f(hh));
            }
            const int lsh = (2 * (cc * 4 + q))     ^ (rec2 & 15);
            const int lsl = (2 * (cc * 4 + q) + 1) ^ (rec2 & 15);
            *reinterpret_cast<ushort4v*>(&lds[rec2 * 128 + lsh * 8 + 4 * h]) = hv;
            *reinterpret_cast<ushort4v*>(&lds[rec2 * 128 + lsl * 8 + 4 * h]) = lv;
        }
    }
    __syncthreads();

    // ---- wc0: 1x1 64->64 from LDS y-tile; wave owns cc output chunk
    f32x16 a2;
    #pragma unroll
    for (int q = 0; q < 4; ++q) {
        f32x4 b4 = *reinterpret_cast<const f32x4*>(&bc0[cc * 32 + q * 8 + 4 * h]);
        #pragma unroll
        for (int r2 = 0; r2 < 4; ++r2) a2[q * 4 + r2] = b4[r2];
    }
    {
        const int rec2 = r * 32 + p;
        #pragma unroll
        for (int rnd = 0; rnd < 4; ++rnd) {
            const int sh = (4 * rnd + 2 * h)     ^ (rec2 & 15);
            const int sl = (4 * rnd + 2 * h + 1) ^ (rec2 & 15);
            short8 Bh = *reinterpret_cast<const short8*>(&lds[rec2 * 128 + sh * 8]);
            short8 Bl = *reinterpret_cast<const short8*>(&lds[rec2 * 128 + sl * 8]);
            const unsigned short* fb = wc0fr + (rnd * 2 + cc) * 1024 + lane * 8;
            short8 Awh = *reinterpret_cast<const short8*>(fb);
            short8 Awl = *reinterpret_cast<const short8*>(fb + 512);
            a2 = __builtin_amdgcn_mfma_f32_32x32x16_bf16(Awh, Bh, a2, 0, 0, 0);
            a2 = __builtin_amdgcn_mfma_f32_32x32x16_bf16(Awh, Bl, a2, 0, 0, 0);
            a2 = __builtin_amdgcn_mfma_f32_32x32x16_bf16(Awl, Bh, a2, 0, 0, 0);
        }
    }

    const int oy = oy0 + r;
    unsigned short* op = ycl + ((long)n * 25600 + (long)oy * 160 + ox0 + p) * 128;
    #pragma unroll
    for (int q = 0; q < 4; ++q) {
        ushort4v hv, lv;
        #pragma unroll
        for (int r2 = 0; r2 < 4; ++r2) {
            float v = silu_f(a2[q * 4 + r2]);
            unsigned short hh = bfhi(v);
            hv[r2] = hh; lv[r2] = bfhi(v - bf2f(hh));
        }
        const int gq = cc * 4 + q;
        *reinterpret_cast<ushort4v*>(op + gq * 16 + 4 * h)     = hv;
        *reinterpret_cast<ushort4v*>(op + gq * 16 + 8 + 4 * h) = lv;
    }
}

// ============ wb: 32->32 s1 3x3, tile-only LDS, frags from global ===========
template <bool RESID>
__global__ __launch_bounds__(512, 4) void wb3x3(
    const unsigned short* __restrict__ in, int inRec, int inSlot0,
    const unsigned short* __restrict__ wfr, const float* __restrict__ bias,
    unsigned short* __restrict__ outb, const unsigned short* __restrict__ resid)
{
    __shared__ unsigned short lds[21760];        // tile 34x10 x 64 ush (43.5 KB)
    const int tid = threadIdx.x;
    const int wv = tid >> 6, lane = tid & 63;
    const int p = lane & 31, h = lane >> 5;
    const int bx = blockIdx.x % 5, by = blockIdx.x / 5;
    const int ox0 = bx * 32, oy0 = by * 8;
    const int n = blockIdx.z;

    for (int u = tid; u < 2720; u += 512) {      // tile 34x10, 8 slots/rec
        const int rec = u >> 3, s = u & 7;
        const int row = rec / 34, col = rec - row * 34;
        const int gr = oy0 - 1 + row, gc = ox0 - 1 + col;
        uint4v val = {0, 0, 0, 0};
        if (gr >= 0 && gr < 160 && gc >= 0 && gc < 160)
            val = *reinterpret_cast<const uint4v*>(
                in + ((long)n * 25600 + gr * 160 + gc) * inRec + (inSlot0 + s) * 8);
        *reinterpret_cast<uint4v*>(&lds[rec * 64 + ((s ^ (rec & 7)) * 8)]) = val;
    }

    f32x16 acc;
    #pragma unroll
    for (int q = 0; q < 4; ++q) {
        f32x4 b4 = *reinterpret_cast<const f32x4*>(&bias[q * 8 + 4 * h]);
        #pragma unroll
        for (int r = 0; r < 4; ++r) acc[q * 4 + r] = b4[r];
    }
    __syncthreads();

    #pragma unroll
    for (int tap = 0; tap < 9; ++tap) {
        const int dy = tap / 3 - 1, dx = tap % 3 - 1;
        const int rec = (wv + dy + 1) * 34 + (p + dx + 1);
        const unsigned short* t = &lds[rec * 64];
        short8 Bh[2], Bl[2];
        #pragma unroll
        for (int rnd = 0; rnd < 2; ++rnd) {
            Bh[rnd] = *reinterpret_cast<const short8*>(t + (((rnd*4 + 2*h)     ^ (rec & 7)) * 8));
            Bl[rnd] = *reinterpret_cast<const short8*>(t + (((rnd*4 + 2*h + 1) ^ (rec & 7)) * 8));
        }
        #pragma unroll
        for (int rnd = 0; rnd < 2; ++rnd) {
            const unsigned short* fb = wfr + (tap * 2 + rnd) * 1024 + lane * 8;
            short8 Awh = *reinterpret_cast<const short8*>(fb);
            short8 Awl = *reinterpret_cast<const short8*>(fb + 512);
            acc = __builtin_amdgcn_mfma_f32_32x32x16_bf16(Awh, Bh[rnd], acc, 0, 0, 0);
            acc = __builtin_amdgcn_mfma_f32_32x32x16_bf16(Awh, Bl[rnd], acc, 0, 0, 0);
            acc = __builtin_amdgcn_mfma_f32_32x32x16_bf16(Awl, Bh[rnd], acc, 0, 0, 0);
        }
    }

    const int oy = oy0 + wv;
    const long prow = (long)n * 25600 + (long)oy * 160 + ox0 + p;
    unsigned short* op = outb + prow * 64;
    const unsigned short* rp = RESID ? resid + prow * 128 : nullptr;
    #pragma unroll
    for (int q = 0; q < 4; ++q) {
        ushort4v hv, lv;
        float vs[4];
        #pragma unroll
        for (int r = 0; r < 4; ++r) vs[r] = silu_f(acc[q * 4 + r]);
        if (RESID) {
            ushort4v rh = *reinterpret_cast<const ushort4v*>(rp + (q + 4) * 16 + 4 * h);
            ushort4v rl = *reinterpret_cast<const ushort4v*>(rp + (q + 4) * 16 + 8 + 4 * h);
            #pragma unroll
            for (int r = 0; r < 4; ++r) vs[r] += bf2f(rh[r]) + bf2f(rl[r]);
        }
        #pragma unroll
        for (int r = 0; r < 4; ++r) {
            unsigned short hh = bfhi(vs[r]);
            hv[r] = hh; lv[r] = bfhi(vs[r] - bf2f(hh));
        }
        *reinterpret_cast<ushort4v*>(op + q * 16 + 4 * h)     = hv;
        *reinterpret_cast<ushort4v*>(op + q * 16 + 8 + 4 * h) = lv;
    }
}

// ============ wc1: 1x1 concat(96->64), zero LDS, frags from global ==========
template <int R1, int R2, bool POUT>
__global__ __launch_bounds__(512, 4) void wc1x1(
    const unsigned short* __restrict__ in1, int rec1,
    const unsigned short* __restrict__ in2, int rec2,
    const unsigned short* __restrict__ wfr, const float* __restrict__ bias,
    unsigned short* __restrict__ outb)
{
    constexpr int RT = R1 + R2;
    const int tid = threadIdx.x;
    const int wv = tid >> 6, lane = tid & 63;
    const int p = lane & 31, h = lane >> 5;
    const int n = blockIdx.z;
    const int px0 = blockIdx.x * 512;

    f32x16 acc[2][2];
    #pragma unroll
    for (int cc = 0; cc < 2; ++cc)
        #pragma unroll
        for (int q = 0; q < 4; ++q) {
            f32x4 b4 = *reinterpret_cast<const f32x4*>(&bias[cc * 32 + q * 8 + 4 * h]);
            #pragma unroll
            for (int r = 0; r < 4; ++r) { acc[cc][0][q*4+r] = b4[r]; acc[cc][1][q*4+r] = b4[r]; }
        }

    #pragma unroll
    for (int rnd = 0; rnd < RT; ++rnd) {
        const unsigned short* bp = (rnd < R1) ? in1 : in2;
        const int recN = (rnd < R1) ? rec1 : rec2;
        const int s0 = 4 * ((rnd < R1) ? rnd : rnd - R1);
        #pragma unroll
        for (int k = 0; k < 2; ++k) {
            const int px = px0 + (wv * 2 + k) * 32 + p;
            const unsigned short* sp = bp + ((long)n * 25600 + px) * recN + (s0 + 2 * h) * 8;
            short8 Bh = *reinterpret_cast<const short8*>(sp);
            short8 Bl = *reinterpret_cast<const short8*>(sp + 8);
            #pragma unroll
            for (int cc = 0; cc < 2; ++cc) {
                const unsigned short* fb = wfr + (rnd * 2 + cc) * 1024 + lane * 8;
                short8 Awh = *reinterpret_cast<const short8*>(fb);
                short8 Awl = *reinterpret_cast<const short8*>(fb + 512);
                acc[cc][k] = __builtin_amdgcn_mfma_f32_32x32x16_bf16(Awh, Bh, acc[cc][k], 0, 0, 0);
                acc[cc][k] = __builtin_amdgcn_mfma_f32_32x32x16_bf16(Awh, Bl, acc[cc][k], 0, 0, 0);
                acc[cc][k] = __builtin_amdgcn_mfma_f32_32x32x16_bf16(Awl, Bh, acc[cc][k], 0, 0, 0);
            }
        }
    }

    #pragma unroll
    for (int k = 0; k < 2; ++k) {
        const int px = px0 + (wv * 2 + k) * 32 + p;
        unsigned short* op;
        if (POUT) {
            const int y = px / 160, xx = px % 160;
            const int pl = (y & 1) * 2 + (xx & 1);
            op = outb + (((long)n * 4 + pl) * 6400 + (y >> 1) * 80 + (xx >> 1)) * 128;
        } else {
            op = outb + ((long)n * 25600 + px) * 128;
        }
        #pragma unroll
        for (int cc = 0; cc < 2; ++cc)
            #pragma unroll
            for (int q = 0; q < 4; ++q) {
                ushort4v hv, lv;
                #pragma unroll
                for (int r = 0; r < 4; ++r) {
                    float v = silu_f(acc[cc][k][q * 4 + r]);
                    unsigned short hh = bfhi(v);
                    hv[r] = hh; lv[r] = bfhi(v - bf2f(hh));
                }
                const int gq = cc * 4 + q;
                *reinterpret_cast<ushort4v*>(op + gq * 16 + 4 * h)     = hv;
                *reinterpret_cast<ushort4v*>(op + gq * 16 + 8 + 4 * h) = lv;
            }
    }
}

// ============ conv3: 64->128 s2 3x3, SINGLE kernel, 4 staging rounds ========
__global__ __launch_bounds__(512, 4) void conv3_one(
    const unsigned short* __restrict__ h2p, const unsigned short* __restrict__ wfr,
    const float* __restrict__ bias, float* __restrict__ outf)
{
    __shared__ unsigned short lds[34848];        // tile 1089 x 32 ush (69.7 KB)
    const int tid = threadIdx.x;
    const int wv = tid >> 6, lane = tid & 63;
    const int p = lane & 31, h = lane >> 5;
    const int bx = blockIdx.x % 5, by = blockIdx.x / 5;
    const int ox0 = bx * 16, oy0 = by * 16;
    const int cg = blockIdx.y;
    const int co0 = cg * 64;
    const int n = blockIdx.z;

    f32x16 acc[2];
    #pragma unroll
    for (int cc = 0; cc < 2; ++cc)
        #pragma unroll
        for (int q = 0; q < 4; ++q) {
            f32x4 b4 = *reinterpret_cast<const f32x4*>(&bias[co0 + cc * 32 + q * 8 + 4 * h]);
            #pragma unroll
            for (int r = 0; r < 4; ++r) acc[cc][q * 4 + r] = b4[r];
        }

    for (int rr = 0; rr < 4; ++rr) {
        __syncthreads();
        for (int u = tid; u < 4356; u += 512) {
            const int rec = u >> 2, s = u & 3;
            int gp, row, col;
            if (rec < 256)      { gp = 0; row = rec >> 4; col = rec & 15; }
            else if (rec < 528) { gp = 1; int r2 = rec - 256; row = r2 / 17; col = r2 - row * 17; }
            else if (rec < 800) { gp = 2; int r2 = rec - 528; row = r2 >> 4; col = r2 & 15; }
            else                { gp = 3; int r2 = rec - 800; row = r2 / 17; col = r2 - row * 17; }
            const int gr = (gp >= 2) ? oy0 - 1 + row : oy0 + row;
            const int gc = (gp & 1)  ? ox0 - 1 + col : ox0 + col;
            uint4v val = {0, 0, 0, 0};
            if (gr >= 0 && gr < 80 && gc >= 0 && gc < 80)
                val = *reinterpret_cast<const uint4v*>(
                    h2p + (((long)n * 4 + gp) * 6400 + gr * 80 + gc) * 128 + (rr * 4 + s) * 8);
            *reinterpret_cast<uint4v*>(&lds[rec * 32 + ((s ^ ((rec >> 1) & 3)) * 8)]) = val;
        }
        __syncthreads();

        #pragma unroll
        for (int tap = 0; tap < 9; ++tap) {
            const int dy = tap / 3 - 1, dx = tap % 3 - 1;
            const int ppy = dy & 1, ppx = dx & 1;
            const int toy = ppy ? ((dy == -1) ? 0 : 1) : 0;
            const int tox = ppx ? ((dx == -1) ? 0 : 1) : 0;
            const int gp = ppy * 2 + ppx;
            const int base = (gp == 0) ? 0 : (gp == 1) ? 256 : (gp == 2) ? 528 : 800;
            const int W = ppx ? 17 : 16;
            const int rl = wv * 2 + (p >> 4), cl = p & 15;
            const int rec = base + (ppy ? (rl + toy) : rl) * W + (cl + tox);
            const unsigned short* t = &lds[rec * 32];
            const int pm = (rec >> 1) & 3;
            short8 Bh = *reinterpret_cast<const short8*>(t + (((2*h)     ^ pm) * 8));
            short8 Bl = *reinterpret_cast<const short8*>(t + (((2*h + 1) ^ pm) * 8));
            #pragma unroll
            for (int cc = 0; cc < 2; ++cc) {
                const unsigned short* fb =
                    wfr + (((cg * 9 + tap) * 4 + rr) * 2 + cc) * 1024 + lane * 8;
                short8 Awh = *reinterpret_cast<const short8*>(fb);
                short8 Awl = *reinterpret_cast<const short8*>(fb + 512);
                acc[cc] = __builtin_amdgcn_mfma_f32_32x32x16_bf16(Awh, Bh, acc[cc], 0, 0, 0);
                acc[cc] = __builtin_amdgcn_mfma_f32_32x32x16_bf16(Awh, Bl, acc[cc], 0, 0, 0);
                acc[cc] = __builtin_amdgcn_mfma_f32_32x32x16_bf16(Awl, Bh, acc[cc], 0, 0, 0);
            }
        }
    }

    const int rl = wv * 2 + (p >> 4);
    const int oy = oy0 + rl;
    const int pxg = oy * 80 + ox0 + (p & 15);
    #pragma unroll
    for (int cc = 0; cc < 2; ++cc)
        #pragma unroll
        for (int q = 0; q < 4; ++q)
            #pragma unroll
            for (int r = 0; r < 4; ++r) {
                const int co = co0 + cc * 32 + q * 8 + 4 * h + r;
                outf[((long)n * 128 + co) * 6400 + pxg] = silu_f(acc[cc][q * 4 + r]);
            }
}

extern "C" void kernel_launch(void* const* d_in, const int* in_sizes, int n_in,
                              void* d_out, int out_size, void* d_ws, size_t ws_size,
                              hipStream_t stream) {
    const float* x   = (const float*)d_in[0];
    const float* w0  = (const float*)d_in[1];
    const float* b0  = (const float*)d_in[2];
    const float* w1  = (const float*)d_in[3];
    const float* b1  = (const float*)d_in[4];
    const float* wc0 = (const float*)d_in[5];
    const float* bc0 = (const float*)d_in[6];
    const float* wb1 = (const float*)d_in[7];
    const float* bb1 = (const float*)d_in[8];
    const float* wb2 = (const float*)d_in[9];
    const float* bb2 = (const float*)d_in[10];
    const float* wc1 = (const float*)d_in[11];
    const float* bc1 = (const float*)d_in[12];
    const float* w3  = (const float*)d_in[13];
    const float* b3  = (const float*)d_in[14];

    unsigned short* u = (unsigned short*)d_ws;
    // ws (ushort offsets), peak 157,286,400 B:
    //   ycl [n][25600][128] @52,428,800 ; b1cl @26,214,400 ; bcl @39,321,600
    //   h2p [n][4][6400][128] @0 ; w3a @26,214,400 (b1cl dead after wb2)
    unsigned short* ycl  = u + 52428800L;
    unsigned short* b1cl = u + 26214400L;
    unsigned short* bcl  = u + 39321600L;
    unsigned short* h2p  = u;
    unsigned short* w3a  = u + 26214400L;

    // small-conv frag arena lives in d_out (conv3 overwrites all of d_out)
    unsigned short* wsa = (unsigned short*)d_out;
    unsigned short* a_conv1 = wsa;
    unsigned short* a_wc0   = wsa + 36 * 1024;
    unsigned short* a_wb1   = wsa + 44 * 1024;
    unsigned short* a_wb2   = wsa + 62 * 1024;
    unsigned short* a_wc1   = wsa + 80 * 1024;

    prep_small<<<dim3(24, 1, 1), dim3(256, 1, 1), 0, stream>>>(
        w1, wc0, wb1, wb2, wc1, w0, wsa);

    // STEM: conv0 + conv1 + wc0 fused -> ycl (no h0 intermediate)
    stem_fused<<<dim3(400, 1, 8), dim3(256, 1, 1), 0, stream>>>(
        x, a_conv1, a_wc0, b0, b1, bc0, ycl);

    wb3x3<false><<<dim3(100, 1, 8), dim3(512, 1, 1), 0, stream>>>(
        ycl, 128, 8, a_wb1, bb1, b1cl, nullptr);

    wb3x3<true><<<dim3(100, 1, 8), dim3(512, 1, 1), 0, stream>>>(
        b1cl, 64, 0, a_wb2, bb2, bcl, ycl);

    prep_w3<<<dim3(36, 1, 1), dim3(256, 1, 1), 0, stream>>>(w3, w3a);

    wc1x1<4, 2, true><<<dim3(50, 1, 8), dim3(512, 1, 1), 0, stream>>>(
        ycl, 128, bcl, 64, a_wc1, bc1, h2p);

    conv3_one<<<dim3(25, 2, 8), dim3(512, 1, 1), 0, stream>>>(h2p, w3a, b3, (float*)d_out);
}